// Round 8
// baseline (22425.174 us; speedup 1.0000x reference)
//
#include <hip/hip_runtime.h>
#include <math.h>
#include <float.h>

#define BATCH   8
#define SEQ     1025
#define GTOK    1024
#define CDIM    768
#define NHEAD   12
#define DHEAD   64
#define NVIEW   6
#define NCLUST  512
#define NGRID   1568
#define NROWS   8200
#define NFEAT   8192

typedef unsigned short bf16;

__device__ __forceinline__ float b2f(bf16 u) {
    union { unsigned int i; float f; } v; v.i = ((unsigned int)u) << 16; return v.f;
}
__device__ __forceinline__ bf16 f2b(float f) {
    union { float f; unsigned int i; } v; v.f = f;
    unsigned int x = v.i;
    return (bf16)((x + 0x7fffu + ((x >> 16) & 1u)) >> 16);
}

__device__ __forceinline__ float block_reduce_sum(float v, float* red) {
    int tid = threadIdx.x;
    red[tid] = v; __syncthreads();
    for (int s = blockDim.x >> 1; s > 0; s >>= 1) {
        if (tid < s) red[tid] += red[tid + s];
        __syncthreads();
    }
    float r = red[0]; __syncthreads();
    return r;
}

__device__ __forceinline__ float gelu_exact(float v) {
    return 0.5f * v * (1.f + erff(v * 0.70710678118654752f));
}
__device__ __forceinline__ float quick_gelu(float v) {
    return v / (1.f + expf(-1.702f * v));
}

// ---------------------------------------------------------------------------
// LayerNorm: one block per row (f32 input, f32 gamma/beta, bf16 out)
// goff: element offset into g/b (per-view)
// ---------------------------------------------------------------------------
__global__ __launch_bounds__(256)
void ln_kernel(const float* __restrict__ x, const float* __restrict__ g,
               const float* __restrict__ b, long long goff, bf16* __restrict__ out)
{
    __shared__ float red[256];
    long long row = blockIdx.x;
    int tid = threadIdx.x;
    long long base = row * CDIM;
    float v0 = x[base + tid], v1 = x[base + tid + 256], v2 = x[base + tid + 512];
    float mean = block_reduce_sum(v0 + v1 + v2, red) * (1.f / CDIM);
    float d0 = v0 - mean, d1 = v1 - mean, d2 = v2 - mean;
    float var = block_reduce_sum(d0 * d0 + d1 * d1 + d2 * d2, red) * (1.f / CDIM);
    float rstd = rsqrtf(var + 1e-5f);
    bf16* orow = out + base;
    orow[tid]       = f2b(d0 * rstd * g[goff + tid]       + b[goff + tid]);
    orow[tid + 256] = f2b(d1 * rstd * g[goff + tid + 256] + b[goff + tid + 256]);
    orow[tid + 512] = f2b(d2 * rstd * g[goff + tid + 512] + b[goff + tid + 512]);
}

// ---------------------------------------------------------------------------
// Tiled GEMM, f32 accumulate, scalar loads.
// C = act(alpha*A@B(^T) + bias) + Res
// ATY: A 0=internal bf16, 1=internal f32
// BSRC: B/bias 0=internal bf16, 1=f32 (input weights)
// OTY: out 0=internal bf16, 1=f32
// RES: 0=none, 1=f32 residual
// 64x64 tile, BK=16, 256 threads, 4x4 micro-tile, batched via blockIdx.z.
// ---------------------------------------------------------------------------
template<int TRANSB, int ATY, int BSRC, int OTY, int RES>
__global__ __launch_bounds__(256)
void gemm_k(const void* __restrict__ Av, const void* __restrict__ B,
            const void* __restrict__ bias, const float* __restrict__ Res,
            void* __restrict__ Cv,
            int M, int N, int K, int lda, int ldb, int ldc, int ldres,
            float alpha, int act, long long boff, long long biasoff,
            long long sA, long long sB, long long sC)
{
    __shared__ float As[16][64];
    __shared__ float Bs[16][64];
    int bz = blockIdx.z;
    int tid = threadIdx.x;
    int tx = tid & 15, ty = tid >> 4;
    int m0 = blockIdx.y * 64, n0 = blockIdx.x * 64;
    long long Aoff = (long long)bz * sA;
    long long Boff = boff + (long long)bz * sB;

    float acc[4][4] = {};
    for (int k0 = 0; k0 < K; k0 += 16) {
        for (int l = tid; l < 16 * 64; l += 256) {
            int r = l >> 4, c = l & 15;
            int gm = m0 + r;
            float v = 0.f;
            if (gm < M) {
                long long ai = Aoff + (long long)gm * lda + (k0 + c);
                v = ATY ? ((const float*)Av)[ai] : b2f(((const bf16*)Av)[ai]);
            }
            As[c][r] = v;
        }
        for (int l = tid; l < 16 * 64; l += 256) {
            int kk = l >> 6, n = l & 63;
            int gn = n0 + n;
            float v = 0.f;
            if (gn < N) {
                long long bi = TRANSB ? (Boff + (long long)gn * ldb + (k0 + kk))
                                      : (Boff + (long long)(k0 + kk) * ldb + gn);
                v = BSRC ? ((const float*)B)[bi] : b2f(((const bf16*)B)[bi]);
            }
            Bs[kk][n] = v;
        }
        __syncthreads();
        #pragma unroll
        for (int kk = 0; kk < 16; ++kk) {
            float a[4], bb[4];
            #pragma unroll
            for (int i = 0; i < 4; ++i) a[i] = As[kk][ty * 4 + i];
            #pragma unroll
            for (int j = 0; j < 4; ++j) bb[j] = Bs[kk][tx * 4 + j];
            #pragma unroll
            for (int i = 0; i < 4; ++i)
                #pragma unroll
                for (int j = 0; j < 4; ++j)
                    acc[i][j] += a[i] * bb[j];
        }
        __syncthreads();
    }

    #pragma unroll
    for (int i = 0; i < 4; ++i) {
        int gm = m0 + ty * 4 + i;
        if (gm >= M) continue;
        #pragma unroll
        for (int j = 0; j < 4; ++j) {
            int gn = n0 + tx * 4 + j;
            if (gn >= N) continue;
            float v = acc[i][j] * alpha;
            if (bias) v += BSRC ? ((const float*)bias)[biasoff + gn]
                                : b2f(((const bf16*)bias)[biasoff + gn]);
            if (act == 1) v = quick_gelu(v);
            if (RES) v += Res[(long long)gm * ldres + gn];
            long long ci = sC * bz + (long long)gm * ldc + gn;
            if (OTY) ((float*)Cv)[ci] = v;
            else     ((bf16*)Cv)[ci] = f2b(v);
        }
    }
}

// ---------------------------------------------------------------------------
// Main attention: one block per (b, q). 12 heads; writes AO (bf16) and the
// head-mean attention row into d_out (f32) at element offset NROWS*CDIM.
// qkv layout: (NROWS, 2304) bf16, q | k | v column blocks.
// ---------------------------------------------------------------------------
__global__ __launch_bounds__(256)
void attn_main_kernel(const bf16* __restrict__ qkv, bf16* __restrict__ attnout,
                      float* __restrict__ out)
{
    __shared__ float qsh[DHEAD];
    __shared__ float sc[SEQ];
    __shared__ float awsh[SEQ];
    __shared__ float red[256];
    int q = blockIdx.x, b = blockIdx.y;
    int tid = threadIdx.x;
    for (int k = tid; k < SEQ; k += 256) awsh[k] = 0.f;
    long long baseb = (long long)b * SEQ;
    long long qrow = (baseb + q) * (3 * CDIM);

    for (int h = 0; h < NHEAD; ++h) {
        __syncthreads();
        if (tid < DHEAD) qsh[tid] = b2f(qkv[qrow + h * DHEAD + tid]) * 0.125f;
        __syncthreads();
        float lmax = -FLT_MAX;
        for (int k = tid; k < SEQ; k += 256) {
            const bf16* kr = qkv + (baseb + k) * (3 * CDIM) + CDIM + h * DHEAD;
            float s = 0.f;
            #pragma unroll
            for (int d = 0; d < DHEAD; ++d) s += qsh[d] * b2f(kr[d]);
            sc[k] = s;
            lmax = fmaxf(lmax, s);
        }
        red[tid] = lmax; __syncthreads();
        for (int st = 128; st > 0; st >>= 1) {
            if (tid < st) red[tid] = fmaxf(red[tid], red[tid + st]);
            __syncthreads();
        }
        float m = red[0]; __syncthreads();
        float ls = 0.f;
        for (int k = tid; k < SEQ; k += 256) {
            float p = expf(sc[k] - m);
            sc[k] = p; ls += p;
        }
        float Z = block_reduce_sum(ls, red);
        float inv = 1.f / fmaxf(Z, 1e-30f);
        for (int k = tid; k < SEQ; k += 256) {
            float p = sc[k] * inv;
            sc[k] = p;
            awsh[k] += p * (1.f / NHEAD);
        }
        __syncthreads();
        int d = tid & 63, kg = tid >> 6;
        float acc = 0.f;
        for (int k = kg; k < SEQ; k += 4)
            acc += sc[k] * b2f(qkv[(baseb + k) * (3 * CDIM) + 2 * CDIM + h * DHEAD + d]);
        red[tid] = acc; __syncthreads();
        if (tid < 64) {
            float t = red[tid] + red[tid + 64] + red[tid + 128] + red[tid + 192];
            attnout[(baseb + q) * CDIM + h * DHEAD + tid] = f2b(t);
        }
        __syncthreads();
    }
    long long awbase = (long long)NROWS * CDIM + (baseb + q) * (long long)SEQ;
    for (int k = tid; k < SEQ; k += 256)
        out[awbase + k] = awsh[k];
}

// ---------------------------------------------------------------------------
// Row softmax on f32 rows of width 1024, in place
// ---------------------------------------------------------------------------
__global__ __launch_bounds__(256)
void softmax_rows(float* __restrict__ s)
{
    __shared__ float red[256];
    long long row = blockIdx.x;
    float* sr = s + row * GTOK;
    int tid = threadIdx.x;
    float v[4];
    float lmax = -FLT_MAX;
    #pragma unroll
    for (int i = 0; i < 4; ++i) { v[i] = sr[tid + i * 256]; lmax = fmaxf(lmax, v[i]); }
    red[tid] = lmax; __syncthreads();
    for (int st = 128; st > 0; st >>= 1) {
        if (tid < st) red[tid] = fmaxf(red[tid], red[tid + st]);
        __syncthreads();
    }
    float m = red[0]; __syncthreads();
    float ls = 0.f;
    #pragma unroll
    for (int i = 0; i < 4; ++i) { v[i] = expf(v[i] - m); ls += v[i]; }
    float Z = block_reduce_sum(ls, red);
    float inv = 1.f / fmaxf(Z, 1e-30f);
    #pragma unroll
    for (int i = 0; i < 4; ++i) sr[tid + i * 256] = v[i] * inv;
}

// ---------------------------------------------------------------------------
// adapter down: adp1 = gelu(ffn @ w_down + b_down) -> f32 (NROWS,16)
// ---------------------------------------------------------------------------
__global__ __launch_bounds__(256)
void adp_down_kernel(const float* __restrict__ ffn, const float* __restrict__ w,
                     const float* __restrict__ bias, float* __restrict__ out)
{
    __shared__ float rowsh[CDIM];
    __shared__ float red[256];
    long long row = blockIdx.x;
    int tid = threadIdx.x;
    for (int c = tid; c < CDIM; c += 256) rowsh[c] = ffn[row * CDIM + c];
    __syncthreads();
    int n = tid >> 4;
    int part = tid & 15;
    float s = 0.f;
    for (int i = part; i < CDIM; i += 16) s += rowsh[i] * w[i * 16 + n];
    red[tid] = s; __syncthreads();
    if (part == 0) {
        float t = 0.f;
        #pragma unroll
        for (int p = 0; p < 16; ++p) t += red[n * 16 + p];
        t += bias[n];
        out[row * 16 + n] = gelu_exact(t);
    }
}

// ---------------------------------------------------------------------------
// final up + residuals: v = x2 + ffn + 0.5*(adp1 @ w_up + b_up)   (f32)
// writes d_out (f32, all rows) and f32 feat (non-cls rows)
// ---------------------------------------------------------------------------
__global__ __launch_bounds__(256)
void final_up_kernel(const float* __restrict__ adp1, const float* __restrict__ w_up,
                     const float* __restrict__ b_up, const float* __restrict__ x2,
                     const float* __restrict__ ffn, float* __restrict__ out,
                     float* __restrict__ feat)
{
    __shared__ float a[16];
    long long row = blockIdx.x;
    int tid = threadIdx.x;
    if (tid < 16) a[tid] = adp1[row * 16 + tid];
    __syncthreads();
    int b = (int)(row / SEQ);
    int s = (int)(row % SEQ);
    #pragma unroll
    for (int i = 0; i < 3; ++i) {
        int c = tid + i * 256;
        float acc = b_up[c];
        #pragma unroll
        for (int k = 0; k < 16; ++k) acc += a[k] * w_up[k * CDIM + c];
        float v = x2[row * CDIM + c] + ffn[row * CDIM + c] + 0.5f * acc;
        out[row * CDIM + c] = v;
        if (s > 0)
            feat[((long long)b * GTOK + (s - 1)) * CDIM + c] = v;
    }
}

// ---------------------------------------------------------------------------
// Deterministic segment max+mean over 8192 f32 rows; y = mx + mn (f32)
// ---------------------------------------------------------------------------
__global__ __launch_bounds__(256)
void seg_kernel(const float* __restrict__ feat, const int* __restrict__ idx,
                float* __restrict__ y)
{
    __shared__ int sidx[NFEAT];
    int seg = blockIdx.x;
    int tid = threadIdx.x;
    for (int j = tid; j < NFEAT; j += 256) sidx[j] = idx[j];
    __syncthreads();
    float mx0 = -FLT_MAX, mx1 = -FLT_MAX, mx2 = -FLT_MAX;
    float s0 = 0.f, s1 = 0.f, s2 = 0.f;
    int cnt = 0;
    for (int j = 0; j < NFEAT; ++j) {
        if (sidx[j] == seg) {
            const float* fr = feat + (long long)j * CDIM;
            float v0 = fr[tid], v1 = fr[tid + 256], v2 = fr[tid + 512];
            s0 += v0; s1 += v1; s2 += v2;
            mx0 = fmaxf(mx0, v0); mx1 = fmaxf(mx1, v1); mx2 = fmaxf(mx2, v2);
            ++cnt;
        }
    }
    if (cnt == 0) { mx0 = mx1 = mx2 = 0.f; }
    float inv = 1.f / (float)(cnt > 0 ? cnt : 1);
    float* yr = y + (long long)seg * CDIM;
    yr[tid]       = mx0 + s0 * inv;
    yr[tid + 256] = mx1 + s1 * inv;
    yr[tid + 512] = mx2 + s2 * inv;
}

// ---------------------------------------------------------------------------
// BatchNorm over rows (two-pass) + exact GELU -> bf16. goff: g/b offset.
// ---------------------------------------------------------------------------
__global__ __launch_bounds__(128)
void bn_gelu_kernel(const float* __restrict__ y, const float* __restrict__ g,
                    const float* __restrict__ b, long long goff,
                    bf16* __restrict__ out, int R)
{
    __shared__ float red[128];
    int c = blockIdx.x;
    int tid = threadIdx.x;
    float s = 0.f;
    for (int r = tid; r < R; r += 128) s += y[(long long)r * CDIM + c];
    float mean = block_reduce_sum(s, red) / (float)R;
    float ss = 0.f;
    for (int r = tid; r < R; r += 128) {
        float d = y[(long long)r * CDIM + c] - mean;
        ss += d * d;
    }
    float var = fmaxf(block_reduce_sum(ss, red) / (float)R, 0.f);
    float rstd = rsqrtf(var + 1e-5f);
    float gc = g[goff + c], bc = b[goff + c];
    for (int r = tid; r < R; r += 128) {
        float v = (y[(long long)r * CDIM + c] - mean) * rstd * gc + bc;
        out[(long long)r * CDIM + c] = f2b(gelu_exact(v));
    }
}

// ---------------------------------------------------------------------------
// Final fusion: cosine sims over 6 views, weighted sum, write f32 out rows.
// ---------------------------------------------------------------------------
__global__ __launch_bounds__(256)
void fuse_final_kernel(const float* __restrict__ feat, const bf16* __restrict__ bn3d,
                       const bf16* __restrict__ bn1d, const int* __restrict__ cluster,
                       const int* __restrict__ fgi, float* __restrict__ out)
{
    __shared__ float red[256];
    __shared__ float simsh[NVIEW];
    int j = blockIdx.x;
    int tid = threadIdx.x;
    int b = j >> 10, g = j & 1023;
    const bf16* x3 = bn3d + (long long)cluster[j] * CDIM;
    float s = 0.f;
    for (int c = tid; c < CDIM; c += 256) { float v = b2f(x3[c]); s += v * v; }
    float nx3 = fmaxf(sqrtf(block_reduce_sum(s, red)), 1e-8f);

    for (int i = 0; i < NVIEW; ++i) {
        const bf16* p = bn1d + ((long long)i * NGRID + fgi[i * NFEAT + j]) * CDIM;
        float d = 0.f, nn = 0.f;
        for (int c = tid; c < CDIM; c += 256) {
            float pv = b2f(p[c]);
            d += pv * b2f(x3[c]); nn += pv * pv;
        }
        float D = block_reduce_sum(d, red);
        float Np = sqrtf(block_reduce_sum(nn, red));
        if (tid == 0) {
            float cosv = D / (fmaxf(Np, 1e-8f) * nx3);
            simsh[i] = (cosv + 1.f) * 0.5f;
        }
        __syncthreads();
    }
    float ssum = 0.f;
    #pragma unroll
    for (int i = 0; i < NVIEW; ++i) ssum += simsh[i];
    float invs = 1.f / fmaxf(ssum, 1e-20f);
    long long orow = ((long long)b * SEQ + 1 + g) * CDIM;
    for (int c = tid; c < CDIM; c += 256) {
        float acc = 0.f;
        #pragma unroll
        for (int i = 0; i < NVIEW; ++i) {
            const bf16* p = bn1d + ((long long)i * NGRID + fgi[i * NFEAT + j]) * CDIM;
            acc += simsh[i] * invs * b2f(p[c]);
        }
        out[orow + c] = feat[(long long)j * CDIM + c] + 0.3f * acc;
    }
}

// ---------------------------------------------------------------------------
// Host side
// ---------------------------------------------------------------------------
extern "C" void kernel_launch(void* const* d_in, const int* in_sizes, int n_in,
                              void* d_out, int out_size, void* d_ws, size_t ws_size,
                              hipStream_t stream)
{
    const float* x      = (const float*)d_in[0];
    const int*  cluster = (const int*)d_in[2];
    const int*  fgi     = (const int*)d_in[3];
    const float* ln1_g = (const float*)d_in[6];
    const float* ln1_b = (const float*)d_in[7];
    const float* w_qkv = (const float*)d_in[8];
    const float* b_qkv = (const float*)d_in[9];
    const float* w_o   = (const float*)d_in[10];
    const float* b_o   = (const float*)d_in[11];
    const float* ln2_g = (const float*)d_in[12];
    const float* ln2_b = (const float*)d_in[13];
    const float* w_fc  = (const float*)d_in[14];
    const float* b_fc  = (const float*)d_in[15];
    const float* w_proj= (const float*)d_in[16];
    const float* b_proj= (const float*)d_in[17];
    const float* w_down= (const float*)d_in[18];
    const float* b_down= (const float*)d_in[19];
    const float* w_up  = (const float*)d_in[20];
    const float* b_up  = (const float*)d_in[21];
    const float* bn3d_g= (const float*)d_in[22];
    const float* bn3d_b= (const float*)d_in[23];
    const float* n3_g  = (const float*)d_in[24];
    const float* n3_b  = (const float*)d_in[25];
    const float* vw_qkv= (const float*)d_in[26];
    const float* vb_qkv= (const float*)d_in[27];
    const float* vw_o  = (const float*)d_in[28];
    const float* vb_o  = (const float*)d_in[29];
    const float* bn1d_g= (const float*)d_in[30];
    const float* bn1d_b= (const float*)d_in[31];
    (void)in_sizes; (void)n_in; (void)out_size; (void)ws_size;

    float* out = (float*)d_out;

    // workspace layout (bytes), total ~185 MB (proven safe in r4-r7)
    char* w = (char*)d_ws;
    bf16*  QKV  = (bf16*)w;  w += (long long)NROWS * 3 * CDIM * 2;    // 37.8 MB
    bf16*  H    = (bf16*)w;  w += (long long)NROWS * CDIM * 2;        // 12.6 MB
    float* X2   = (float*)w; w += (long long)NROWS * CDIM * 4;        // 25.2 MB
    bf16*  AO   = (bf16*)w;  w += (long long)NROWS * CDIM * 2;        // 12.6 MB
    float* FFN  = (float*)w; w += (long long)NROWS * CDIM * 4;        // 25.2 MB
    float* T1   = (float*)w; w += (long long)BATCH * GTOK * GTOK * 4; // 33.5 MB
    float* ADP  = (float*)w; w += (long long)NROWS * 16 * 4;          // 0.5 MB
    float* FEAT = (float*)w; w += (long long)NFEAT * CDIM * 4;        // 25.2 MB
    float* Y512 = (float*)w; w += (long long)NCLUST * CDIM * 4;       // 1.6 MB
    bf16*  BN3D = (bf16*)w;  w += (long long)NCLUST * CDIM * 2;       // 0.8 MB
    float* YG   = (float*)w; w += (long long)NGRID * CDIM * 4;        // 4.8 MB
    bf16*  BN1D = (bf16*)w;  w += (long long)NVIEW * NGRID * CDIM * 2;// 14.5 MB

    dim3 blk(256);

    // ---- stage A: transformer block ----
    ln_kernel<<<NROWS, blk, 0, stream>>>(x, ln1_g, ln1_b, 0LL, H);

    gemm_k<0,0,1,0,0><<<dim3(36, 129, 1), blk, 0, stream>>>(
        H, w_qkv, b_qkv, nullptr, QKV,
        NROWS, 3*CDIM, CDIM, CDIM, 3*CDIM, 3*CDIM, 0, 1.f, 0, 0LL, 0LL, 0, 0, 0);

    attn_main_kernel<<<dim3(SEQ, BATCH), blk, 0, stream>>>(QKV, AO, out);

    // x2 = AO @ w_o + b_o + x   -> f32
    gemm_k<0,0,1,1,1><<<dim3(12, 129, 1), blk, 0, stream>>>(
        AO, w_o, b_o, x, X2,
        NROWS, CDIM, CDIM, CDIM, CDIM, CDIM, CDIM, 1.f, 0, 0LL, 0LL, 0, 0, 0);

    ln_kernel<<<NROWS, blk, 0, stream>>>(X2, ln2_g, ln2_b, 0LL, H);

    // FC + proj in 2 row-chunks of 4100; bf16 MID shares T1 (25.2MB <= 33.5MB)
    {
        bf16* MID = (bf16*)T1;
        for (int cidx = 0; cidx < 2; ++cidx) {
            long long r0 = 4100LL * cidx;
            int m = 4100;
            gemm_k<0,0,1,0,0><<<dim3(48, 65, 1), blk, 0, stream>>>(
                H + r0 * CDIM, w_fc, b_fc, nullptr, MID,
                m, 4*CDIM, CDIM, CDIM, 4*CDIM, 4*CDIM, 0, 1.f, 1, 0LL, 0LL, 0, 0, 0);
            gemm_k<0,0,1,1,0><<<dim3(12, 65, 1), blk, 0, stream>>>(
                MID, w_proj, b_proj, nullptr, FFN + r0 * CDIM,
                m, CDIM, 4*CDIM, 4*CDIM, CDIM, CDIM, 0, 1.f, 0, 0LL, 0LL, 0, 0, 0);
        }
    }

    adp_down_kernel<<<NROWS, blk, 0, stream>>>(FFN, w_down, b_down, ADP);
    final_up_kernel<<<NROWS, blk, 0, stream>>>(ADP, w_up, b_up, X2, FFN, out, FEAT);

    // ---- stage B: cluster pooling + BN-GELU ----
    seg_kernel<<<NCLUST, blk, 0, stream>>>(FEAT, cluster, Y512);
    bn_gelu_kernel<<<CDIM, dim3(128), 0, stream>>>(Y512, bn3d_g, bn3d_b, 0LL, BN3D, NCLUST);

    // ---- stage C: 6 views ----
    const float inv_sqrt_c = 0.03608439182435161f; // 1/sqrt(768)
    for (int i = 0; i < NVIEW; ++i) {
        ln_kernel<<<NFEAT, blk, 0, stream>>>(FEAT, n3_g, n3_b, (long long)i * CDIM, H);

        gemm_k<0,0,1,0,0><<<dim3(36, 128, 1), blk, 0, stream>>>(
            H, vw_qkv, vb_qkv, nullptr, QKV,
            NFEAT, 3*CDIM, CDIM, CDIM, 3*CDIM, 3*CDIM, 0, 1.f, 0,
            (long long)i * CDIM * 3*CDIM, (long long)i * 3*CDIM, 0, 0, 0);

        // scores = q1 @ k1^T / sqrt(C) (f32 out, batched over 8)
        gemm_k<1,0,0,1,0><<<dim3(16, 16, BATCH), blk, 0, stream>>>(
            QKV, QKV + CDIM, nullptr, nullptr, T1,
            GTOK, GTOK, CDIM, 3*CDIM, 3*CDIM, GTOK, 0, inv_sqrt_c, 0, 0LL, 0LL,
            (long long)GTOK * 3*CDIM, (long long)GTOK * 3*CDIM, (long long)GTOK * GTOK);

        softmax_rows<<<BATCH * GTOK, blk, 0, stream>>>(T1);

        // o1 = a1 @ v1 (A f32, batched over 8) -> AO (bf16)
        gemm_k<0,1,0,0,0><<<dim3(12, 16, BATCH), blk, 0, stream>>>(
            T1, QKV + 2*CDIM, nullptr, nullptr, AO,
            GTOK, CDIM, GTOK, GTOK, 3*CDIM, CDIM, 0, 1.f, 0, 0LL, 0LL,
            (long long)GTOK * GTOK, (long long)GTOK * 3*CDIM, (long long)GTOK * CDIM);

        // fx = o1 @ vw_o + vb_o + feat -> X2 (f32)
        gemm_k<0,0,1,1,1><<<dim3(12, 128, 1), blk, 0, stream>>>(
            AO, vw_o, vb_o, FEAT, X2,
            NFEAT, CDIM, CDIM, CDIM, CDIM, CDIM, CDIM, 1.f, 0,
            (long long)i * CDIM * CDIM, (long long)i * CDIM, 0, 0, 0);

        seg_kernel<<<NGRID, blk, 0, stream>>>(X2, fgi + i * NFEAT, YG);
        bn_gelu_kernel<<<CDIM, dim3(128), 0, stream>>>(
            YG, bn1d_g, bn1d_b, (long long)i * CDIM,
            BN1D + (long long)i * NGRID * CDIM, NGRID);
    }

    // ---- final fusion ----
    fuse_final_kernel<<<NFEAT, blk, 0, stream>>>(FEAT, BN3D, BN1D, cluster, fgi, out);
}

// Round 9
// 16856.250 us; speedup vs baseline: 1.3304x; 1.3304x over previous
//
#include <hip/hip_runtime.h>
#include <math.h>
#include <float.h>

#define BATCH   8
#define SEQ     1025
#define GTOK    1024
#define CDIM    768
#define NHEAD   12
#define DHEAD   64
#define NVIEW   6
#define NCLUST  512
#define NGRID   1568
#define NROWS   8200
#define NFEAT   8192

typedef unsigned short bf16;
typedef __attribute__((ext_vector_type(8))) short bf16x8;
typedef __attribute__((ext_vector_type(4))) float f32x4;

__device__ __forceinline__ float b2f(bf16 u) {
    union { unsigned int i; float f; } v; v.i = ((unsigned int)u) << 16; return v.f;
}
__device__ __forceinline__ bf16 f2b(float f) {
    union { float f; unsigned int i; } v; v.f = f;
    unsigned int x = v.i;
    return (bf16)((x + 0x7fffu + ((x >> 16) & 1u)) >> 16);
}

__device__ __forceinline__ float block_reduce_sum(float v, float* red) {
    int tid = threadIdx.x;
    red[tid] = v; __syncthreads();
    for (int s = blockDim.x >> 1; s > 0; s >>= 1) {
        if (tid < s) red[tid] += red[tid + s];
        __syncthreads();
    }
    float r = red[0]; __syncthreads();
    return r;
}

__device__ __forceinline__ float gelu_exact(float v) {
    return 0.5f * v * (1.f + erff(v * 0.70710678118654752f));
}
__device__ __forceinline__ float quick_gelu(float v) {
    return v / (1.f + expf(-1.702f * v));
}

// ---------------------------------------------------------------------------
// LayerNorm: one block per row (f32 input, f32 gamma/beta, bf16 out)
// ---------------------------------------------------------------------------
__global__ __launch_bounds__(256)
void ln_kernel(const float* __restrict__ x, const float* __restrict__ g,
               const float* __restrict__ b, long long goff, bf16* __restrict__ out)
{
    __shared__ float red[256];
    long long row = blockIdx.x;
    int tid = threadIdx.x;
    long long base = row * CDIM;
    float v0 = x[base + tid], v1 = x[base + tid + 256], v2 = x[base + tid + 512];
    float mean = block_reduce_sum(v0 + v1 + v2, red) * (1.f / CDIM);
    float d0 = v0 - mean, d1 = v1 - mean, d2 = v2 - mean;
    float var = block_reduce_sum(d0 * d0 + d1 * d1 + d2 * d2, red) * (1.f / CDIM);
    float rstd = rsqrtf(var + 1e-5f);
    bf16* orow = out + base;
    orow[tid]       = f2b(d0 * rstd * g[goff + tid]       + b[goff + tid]);
    orow[tid + 256] = f2b(d1 * rstd * g[goff + tid + 256] + b[goff + tid + 256]);
    orow[tid + 512] = f2b(d2 * rstd * g[goff + tid + 512] + b[goff + tid + 512]);
}

// ---------------------------------------------------------------------------
// MFMA bf16 GEMM: C = act(alpha*A@B(^T) + bias) + Res
// Same interface as before. 64x64 tile, BK=32, 4 waves (32x32 quadrant each),
// v_mfma_f32_16x16x32_bf16 with 2x2 fragments. f32 sources converted to bf16
// during LDS staging. All edges zero-padded/guarded.
// ATY: A 0=bf16, 1=f32 | BSRC: B/bias 0=bf16, 1=f32 | OTY: out 0=bf16, 1=f32
// RES: 0=none, 1=f32 residual
// ---------------------------------------------------------------------------
#define LDSK 40   // LDS row stride in elements (16B aligned, 2-way conflicts only)

template<int TRANSB, int ATY, int BSRC, int OTY, int RES>
__global__ __launch_bounds__(256)
void gemm_k(const void* __restrict__ Av, const void* __restrict__ B,
            const void* __restrict__ bias, const float* __restrict__ Res,
            void* __restrict__ Cv,
            int M, int N, int K, int lda, int ldb, int ldc, int ldres,
            float alpha, int act, long long boff, long long biasoff,
            long long sA, long long sB, long long sC)
{
    __shared__ short As[64][LDSK];
    __shared__ short Bs[64][LDSK];
    int bz = blockIdx.z;
    int tid = threadIdx.x;
    int m0 = blockIdx.y * 64, n0 = blockIdx.x * 64;
    long long Aoff = (long long)bz * sA;
    long long Boff = boff + (long long)bz * sB;

    int lane = tid & 63;
    int w = tid >> 6;
    int wr = w >> 1, wc = w & 1;
    int fr = lane & 15;      // fragment row (A) / col (B,D)
    int kg = lane >> 4;      // k-group 0..3

    f32x4 acc[2][2] = {};

    for (int k0 = 0; k0 < K; k0 += 32) {
        // ---- stage A tile: As[r][k], thread t loads 8 contiguous k of one row
        {
            int r = tid >> 2, kb = (tid & 3) * 8;
            int gm = m0 + r;
            short tmp[8] = {};
            if (gm < M) {
                long long base = Aoff + (long long)gm * lda + k0 + kb;
                if (k0 + kb + 8 <= K) {
                    if (ATY == 0) {
                        *reinterpret_cast<uint4*>(tmp) =
                            *reinterpret_cast<const uint4*>((const bf16*)Av + base);
                    } else {
                        float4 f0 = *reinterpret_cast<const float4*>((const float*)Av + base);
                        float4 f1 = *reinterpret_cast<const float4*>((const float*)Av + base + 4);
                        tmp[0]=(short)f2b(f0.x); tmp[1]=(short)f2b(f0.y);
                        tmp[2]=(short)f2b(f0.z); tmp[3]=(short)f2b(f0.w);
                        tmp[4]=(short)f2b(f1.x); tmp[5]=(short)f2b(f1.y);
                        tmp[6]=(short)f2b(f1.z); tmp[7]=(short)f2b(f1.w);
                    }
                } else {
                    #pragma unroll
                    for (int j = 0; j < 8; ++j) {
                        if (k0 + kb + j < K)
                            tmp[j] = ATY ? (short)f2b(((const float*)Av)[base + j])
                                         : (short)((const bf16*)Av)[base + j];
                    }
                }
            }
            *reinterpret_cast<uint4*>(&As[r][kb]) = *reinterpret_cast<uint4*>(tmp);
        }
        // ---- stage B tile: Bs[col][k]
        {
            int col = tid >> 2, kb = (tid & 3) * 8;
            int gn = n0 + col;
            short tmp[8] = {};
            if (gn < N) {
                if (TRANSB) {
                    long long base = Boff + (long long)gn * ldb + k0 + kb;
                    if (k0 + kb + 8 <= K) {
                        if (BSRC == 0) {
                            *reinterpret_cast<uint4*>(tmp) =
                                *reinterpret_cast<const uint4*>((const bf16*)B + base);
                        } else {
                            float4 f0 = *reinterpret_cast<const float4*>((const float*)B + base);
                            float4 f1 = *reinterpret_cast<const float4*>((const float*)B + base + 4);
                            tmp[0]=(short)f2b(f0.x); tmp[1]=(short)f2b(f0.y);
                            tmp[2]=(short)f2b(f0.z); tmp[3]=(short)f2b(f0.w);
                            tmp[4]=(short)f2b(f1.x); tmp[5]=(short)f2b(f1.y);
                            tmp[6]=(short)f2b(f1.z); tmp[7]=(short)f2b(f1.w);
                        }
                    } else {
                        #pragma unroll
                        for (int j = 0; j < 8; ++j) {
                            if (k0 + kb + j < K)
                                tmp[j] = BSRC ? (short)f2b(((const float*)B)[base + j])
                                              : (short)((const bf16*)B)[base + j];
                        }
                    }
                } else {
                    #pragma unroll
                    for (int j = 0; j < 8; ++j) {
                        int kk = k0 + kb + j;
                        if (kk < K) {
                            long long bi = Boff + (long long)kk * ldb + gn;
                            tmp[j] = BSRC ? (short)f2b(((const float*)B)[bi])
                                          : (short)((const bf16*)B)[bi];
                        }
                    }
                }
            }
            *reinterpret_cast<uint4*>(&Bs[col][kb]) = *reinterpret_cast<uint4*>(tmp);
        }
        __syncthreads();

        // ---- MFMA: each wave does 2x2 fragments of its 32x32 quadrant
        bf16x8 a0 = *reinterpret_cast<const bf16x8*>(&As[wr * 32 + fr][kg * 8]);
        bf16x8 a1 = *reinterpret_cast<const bf16x8*>(&As[wr * 32 + 16 + fr][kg * 8]);
        bf16x8 b0 = *reinterpret_cast<const bf16x8*>(&Bs[wc * 32 + fr][kg * 8]);
        bf16x8 b1 = *reinterpret_cast<const bf16x8*>(&Bs[wc * 32 + 16 + fr][kg * 8]);
        acc[0][0] = __builtin_amdgcn_mfma_f32_16x16x32_bf16(a0, b0, acc[0][0], 0, 0, 0);
        acc[0][1] = __builtin_amdgcn_mfma_f32_16x16x32_bf16(a0, b1, acc[0][1], 0, 0, 0);
        acc[1][0] = __builtin_amdgcn_mfma_f32_16x16x32_bf16(a1, b0, acc[1][0], 0, 0, 0);
        acc[1][1] = __builtin_amdgcn_mfma_f32_16x16x32_bf16(a1, b1, acc[1][1], 0, 0, 0);
        __syncthreads();
    }

    // ---- epilogue: D[row=(lane>>4)*4+i][col=lane&15] per fragment
    #pragma unroll
    for (int m = 0; m < 2; ++m) {
        #pragma unroll
        for (int n = 0; n < 2; ++n) {
            #pragma unroll
            for (int i = 0; i < 4; ++i) {
                int gm = m0 + wr * 32 + m * 16 + kg * 4 + i;
                int gn = n0 + wc * 32 + n * 16 + fr;
                if (gm >= M || gn >= N) continue;
                float v = acc[m][n][i] * alpha;
                if (bias) v += BSRC ? ((const float*)bias)[biasoff + gn]
                                    : b2f(((const bf16*)bias)[biasoff + gn]);
                if (act == 1) v = quick_gelu(v);
                if (RES) v += Res[(long long)gm * ldres + gn];
                long long ci = sC * bz + (long long)gm * ldc + gn;
                if (OTY) ((float*)Cv)[ci] = v;
                else     ((bf16*)Cv)[ci] = f2b(v);
            }
        }
    }
}

// ---------------------------------------------------------------------------
// Main attention: one block per (b, q). 12 heads; writes AO (bf16) and the
// head-mean attention row into d_out (f32) at element offset NROWS*CDIM.
// ---------------------------------------------------------------------------
__global__ __launch_bounds__(256)
void attn_main_kernel(const bf16* __restrict__ qkv, bf16* __restrict__ attnout,
                      float* __restrict__ out)
{
    __shared__ float qsh[DHEAD];
    __shared__ float sc[SEQ];
    __shared__ float awsh[SEQ];
    __shared__ float red[256];
    int q = blockIdx.x, b = blockIdx.y;
    int tid = threadIdx.x;
    for (int k = tid; k < SEQ; k += 256) awsh[k] = 0.f;
    long long baseb = (long long)b * SEQ;
    long long qrow = (baseb + q) * (3 * CDIM);

    for (int h = 0; h < NHEAD; ++h) {
        __syncthreads();
        if (tid < DHEAD) qsh[tid] = b2f(qkv[qrow + h * DHEAD + tid]) * 0.125f;
        __syncthreads();
        float lmax = -FLT_MAX;
        for (int k = tid; k < SEQ; k += 256) {
            const bf16* kr = qkv + (baseb + k) * (3 * CDIM) + CDIM + h * DHEAD;
            float s = 0.f;
            #pragma unroll
            for (int d = 0; d < DHEAD; ++d) s += qsh[d] * b2f(kr[d]);
            sc[k] = s;
            lmax = fmaxf(lmax, s);
        }
        red[tid] = lmax; __syncthreads();
        for (int st = 128; st > 0; st >>= 1) {
            if (tid < st) red[tid] = fmaxf(red[tid], red[tid + st]);
            __syncthreads();
        }
        float m = red[0]; __syncthreads();
        float ls = 0.f;
        for (int k = tid; k < SEQ; k += 256) {
            float p = expf(sc[k] - m);
            sc[k] = p; ls += p;
        }
        float Z = block_reduce_sum(ls, red);
        float inv = 1.f / fmaxf(Z, 1e-30f);
        for (int k = tid; k < SEQ; k += 256) {
            float p = sc[k] * inv;
            sc[k] = p;
            awsh[k] += p * (1.f / NHEAD);
        }
        __syncthreads();
        int d = tid & 63, kg = tid >> 6;
        float acc = 0.f;
        for (int k = kg; k < SEQ; k += 4)
            acc += sc[k] * b2f(qkv[(baseb + k) * (3 * CDIM) + 2 * CDIM + h * DHEAD + d]);
        red[tid] = acc; __syncthreads();
        if (tid < 64) {
            float t = red[tid] + red[tid + 64] + red[tid + 128] + red[tid + 192];
            attnout[(baseb + q) * CDIM + h * DHEAD + tid] = f2b(t);
        }
        __syncthreads();
    }
    long long awbase = (long long)NROWS * CDIM + (baseb + q) * (long long)SEQ;
    for (int k = tid; k < SEQ; k += 256)
        out[awbase + k] = awsh[k];
}

// ---------------------------------------------------------------------------
// Row softmax on f32 rows of width 1024, in place
// ---------------------------------------------------------------------------
__global__ __launch_bounds__(256)
void softmax_rows(float* __restrict__ s)
{
    __shared__ float red[256];
    long long row = blockIdx.x;
    float* sr = s + row * GTOK;
    int tid = threadIdx.x;
    float v[4];
    float lmax = -FLT_MAX;
    #pragma unroll
    for (int i = 0; i < 4; ++i) { v[i] = sr[tid + i * 256]; lmax = fmaxf(lmax, v[i]); }
    red[tid] = lmax; __syncthreads();
    for (int st = 128; st > 0; st >>= 1) {
        if (tid < st) red[tid] = fmaxf(red[tid], red[tid + st]);
        __syncthreads();
    }
    float m = red[0]; __syncthreads();
    float ls = 0.f;
    #pragma unroll
    for (int i = 0; i < 4; ++i) { v[i] = expf(v[i] - m); ls += v[i]; }
    float Z = block_reduce_sum(ls, red);
    float inv = 1.f / fmaxf(Z, 1e-30f);
    #pragma unroll
    for (int i = 0; i < 4; ++i) sr[tid + i * 256] = v[i] * inv;
}

// ---------------------------------------------------------------------------
// adapter down: adp1 = gelu(ffn @ w_down + b_down) -> f32 (NROWS,16)
// ---------------------------------------------------------------------------
__global__ __launch_bounds__(256)
void adp_down_kernel(const float* __restrict__ ffn, const float* __restrict__ w,
                     const float* __restrict__ bias, float* __restrict__ out)
{
    __shared__ float rowsh[CDIM];
    __shared__ float red[256];
    long long row = blockIdx.x;
    int tid = threadIdx.x;
    for (int c = tid; c < CDIM; c += 256) rowsh[c] = ffn[row * CDIM + c];
    __syncthreads();
    int n = tid >> 4;
    int part = tid & 15;
    float s = 0.f;
    for (int i = part; i < CDIM; i += 16) s += rowsh[i] * w[i * 16 + n];
    red[tid] = s; __syncthreads();
    if (part == 0) {
        float t = 0.f;
        #pragma unroll
        for (int p = 0; p < 16; ++p) t += red[n * 16 + p];
        t += bias[n];
        out[row * 16 + n] = gelu_exact(t);
    }
}

// ---------------------------------------------------------------------------
// final up + residuals: v = x2 + ffn + 0.5*(adp1 @ w_up + b_up)   (f32)
// ---------------------------------------------------------------------------
__global__ __launch_bounds__(256)
void final_up_kernel(const float* __restrict__ adp1, const float* __restrict__ w_up,
                     const float* __restrict__ b_up, const float* __restrict__ x2,
                     const float* __restrict__ ffn, float* __restrict__ out,
                     float* __restrict__ feat)
{
    __shared__ float a[16];
    long long row = blockIdx.x;
    int tid = threadIdx.x;
    if (tid < 16) a[tid] = adp1[row * 16 + tid];
    __syncthreads();
    int b = (int)(row / SEQ);
    int s = (int)(row % SEQ);
    #pragma unroll
    for (int i = 0; i < 3; ++i) {
        int c = tid + i * 256;
        float acc = b_up[c];
        #pragma unroll
        for (int k = 0; k < 16; ++k) acc += a[k] * w_up[k * CDIM + c];
        float v = x2[row * CDIM + c] + ffn[row * CDIM + c] + 0.5f * acc;
        out[row * CDIM + c] = v;
        if (s > 0)
            feat[((long long)b * GTOK + (s - 1)) * CDIM + c] = v;
    }
}

// ---------------------------------------------------------------------------
// Deterministic segment max+mean over 8192 f32 rows; y = mx + mn (f32)
// ---------------------------------------------------------------------------
__global__ __launch_bounds__(256)
void seg_kernel(const float* __restrict__ feat, const int* __restrict__ idx,
                float* __restrict__ y)
{
    __shared__ int sidx[NFEAT];
    int seg = blockIdx.x;
    int tid = threadIdx.x;
    for (int j = tid; j < NFEAT; j += 256) sidx[j] = idx[j];
    __syncthreads();
    float mx0 = -FLT_MAX, mx1 = -FLT_MAX, mx2 = -FLT_MAX;
    float s0 = 0.f, s1 = 0.f, s2 = 0.f;
    int cnt = 0;
    for (int j = 0; j < NFEAT; ++j) {
        if (sidx[j] == seg) {
            const float* fr = feat + (long long)j * CDIM;
            float v0 = fr[tid], v1 = fr[tid + 256], v2 = fr[tid + 512];
            s0 += v0; s1 += v1; s2 += v2;
            mx0 = fmaxf(mx0, v0); mx1 = fmaxf(mx1, v1); mx2 = fmaxf(mx2, v2);
            ++cnt;
        }
    }
    if (cnt == 0) { mx0 = mx1 = mx2 = 0.f; }
    float inv = 1.f / (float)(cnt > 0 ? cnt : 1);
    float* yr = y + (long long)seg * CDIM;
    yr[tid]       = mx0 + s0 * inv;
    yr[tid + 256] = mx1 + s1 * inv;
    yr[tid + 512] = mx2 + s2 * inv;
}

// ---------------------------------------------------------------------------
// BatchNorm over rows (two-pass) + exact GELU -> bf16
// ---------------------------------------------------------------------------
__global__ __launch_bounds__(128)
void bn_gelu_kernel(const float* __restrict__ y, const float* __restrict__ g,
                    const float* __restrict__ b, long long goff,
                    bf16* __restrict__ out, int R)
{
    __shared__ float red[128];
    int c = blockIdx.x;
    int tid = threadIdx.x;
    float s = 0.f;
    for (int r = tid; r < R; r += 128) s += y[(long long)r * CDIM + c];
    float mean = block_reduce_sum(s, red) / (float)R;
    float ss = 0.f;
    for (int r = tid; r < R; r += 128) {
        float d = y[(long long)r * CDIM + c] - mean;
        ss += d * d;
    }
    float var = fmaxf(block_reduce_sum(ss, red) / (float)R, 0.f);
    float rstd = rsqrtf(var + 1e-5f);
    float gc = g[goff + c], bc = b[goff + c];
    for (int r = tid; r < R; r += 128) {
        float v = (y[(long long)r * CDIM + c] - mean) * rstd * gc + bc;
        out[(long long)r * CDIM + c] = f2b(gelu_exact(v));
    }
}

// ---------------------------------------------------------------------------
// Final fusion: cosine sims over 6 views, weighted sum, write f32 out rows
// ---------------------------------------------------------------------------
__global__ __launch_bounds__(256)
void fuse_final_kernel(const float* __restrict__ feat, const bf16* __restrict__ bn3d,
                       const bf16* __restrict__ bn1d, const int* __restrict__ cluster,
                       const int* __restrict__ fgi, float* __restrict__ out)
{
    __shared__ float red[256];
    __shared__ float simsh[NVIEW];
    int j = blockIdx.x;
    int tid = threadIdx.x;
    int b = j >> 10, g = j & 1023;
    const bf16* x3 = bn3d + (long long)cluster[j] * CDIM;
    float s = 0.f;
    for (int c = tid; c < CDIM; c += 256) { float v = b2f(x3[c]); s += v * v; }
    float nx3 = fmaxf(sqrtf(block_reduce_sum(s, red)), 1e-8f);

    for (int i = 0; i < NVIEW; ++i) {
        const bf16* p = bn1d + ((long long)i * NGRID + fgi[i * NFEAT + j]) * CDIM;
        float d = 0.f, nn = 0.f;
        for (int c = tid; c < CDIM; c += 256) {
            float pv = b2f(p[c]);
            d += pv * b2f(x3[c]); nn += pv * pv;
        }
        float D = block_reduce_sum(d, red);
        float Np = sqrtf(block_reduce_sum(nn, red));
        if (tid == 0) {
            float cosv = D / (fmaxf(Np, 1e-8f) * nx3);
            simsh[i] = (cosv + 1.f) * 0.5f;
        }
        __syncthreads();
    }
    float ssum = 0.f;
    #pragma unroll
    for (int i = 0; i < NVIEW; ++i) ssum += simsh[i];
    float invs = 1.f / fmaxf(ssum, 1e-20f);
    long long orow = ((long long)b * SEQ + 1 + g) * CDIM;
    for (int c = tid; c < CDIM; c += 256) {
        float acc = 0.f;
        #pragma unroll
        for (int i = 0; i < NVIEW; ++i) {
            const bf16* p = bn1d + ((long long)i * NGRID + fgi[i * NFEAT + j]) * CDIM;
            acc += simsh[i] * invs * b2f(p[c]);
        }
        out[orow + c] = feat[(long long)j * CDIM + c] + 0.3f * acc;
    }
}

// ---------------------------------------------------------------------------
// Host side
// ---------------------------------------------------------------------------
extern "C" void kernel_launch(void* const* d_in, const int* in_sizes, int n_in,
                              void* d_out, int out_size, void* d_ws, size_t ws_size,
                              hipStream_t stream)
{
    const float* x      = (const float*)d_in[0];
    const int*  cluster = (const int*)d_in[2];
    const int*  fgi     = (const int*)d_in[3];
    const float* ln1_g = (const float*)d_in[6];
    const float* ln1_b = (const float*)d_in[7];
    const float* w_qkv = (const float*)d_in[8];
    const float* b_qkv = (const float*)d_in[9];
    const float* w_o   = (const float*)d_in[10];
    const float* b_o   = (const float*)d_in[11];
    const float* ln2_g = (const float*)d_in[12];
    const float* ln2_b = (const float*)d_in[13];
    const float* w_fc  = (const float*)d_in[14];
    const float* b_fc  = (const float*)d_in[15];
    const float* w_proj= (const float*)d_in[16];
    const float* b_proj= (const float*)d_in[17];
    const float* w_down= (const float*)d_in[18];
    const float* b_down= (const float*)d_in[19];
    const float* w_up  = (const float*)d_in[20];
    const float* b_up  = (const float*)d_in[21];
    const float* bn3d_g= (const float*)d_in[22];
    const float* bn3d_b= (const float*)d_in[23];
    const float* n3_g  = (const float*)d_in[24];
    const float* n3_b  = (const float*)d_in[25];
    const float* vw_qkv= (const float*)d_in[26];
    const float* vb_qkv= (const float*)d_in[27];
    const float* vw_o  = (const float*)d_in[28];
    const float* vb_o  = (const float*)d_in[29];
    const float* bn1d_g= (const float*)d_in[30];
    const float* bn1d_b= (const float*)d_in[31];
    (void)in_sizes; (void)n_in; (void)out_size; (void)ws_size;

    float* out = (float*)d_out;

    // workspace layout (bytes), total ~185 MB (proven safe in r4-r8)
    char* w = (char*)d_ws;
    bf16*  QKV  = (bf16*)w;  w += (long long)NROWS * 3 * CDIM * 2;    // 37.8 MB
    bf16*  H    = (bf16*)w;  w += (long long)NROWS * CDIM * 2;        // 12.6 MB
    float* X2   = (float*)w; w += (long long)NROWS * CDIM * 4;        // 25.2 MB
    bf16*  AO   = (bf16*)w;  w += (long long)NROWS * CDIM * 2;        // 12.6 MB
    float* FFN  = (float*)w; w += (long long)NROWS * CDIM * 4;        // 25.2 MB
    float* T1   = (float*)w; w += (long long)BATCH * GTOK * GTOK * 4; // 33.5 MB
    float* ADP  = (float*)w; w += (long long)NROWS * 16 * 4;          // 0.5 MB
    float* FEAT = (float*)w; w += (long long)NFEAT * CDIM * 4;        // 25.2 MB
    float* Y512 = (float*)w; w += (long long)NCLUST * CDIM * 4;       // 1.6 MB
    bf16*  BN3D = (bf16*)w;  w += (long long)NCLUST * CDIM * 2;       // 0.8 MB
    float* YG   = (float*)w; w += (long long)NGRID * CDIM * 4;        // 4.8 MB
    bf16*  BN1D = (bf16*)w;  w += (long long)NVIEW * NGRID * CDIM * 2;// 14.5 MB

    dim3 blk(256);

    // ---- stage A: transformer block ----
    ln_kernel<<<NROWS, blk, 0, stream>>>(x, ln1_g, ln1_b, 0LL, H);

    gemm_k<0,0,1,0,0><<<dim3(36, 129, 1), blk, 0, stream>>>(
        H, w_qkv, b_qkv, nullptr, QKV,
        NROWS, 3*CDIM, CDIM, CDIM, 3*CDIM, 3*CDIM, 0, 1.f, 0, 0LL, 0LL, 0, 0, 0);

    attn_main_kernel<<<dim3(SEQ, BATCH), blk, 0, stream>>>(QKV, AO, out);

    // x2 = AO @ w_o + b_o + x   -> f32
    gemm_k<0,0,1,1,1><<<dim3(12, 129, 1), blk, 0, stream>>>(
        AO, w_o, b_o, x, X2,
        NROWS, CDIM, CDIM, CDIM, CDIM, CDIM, CDIM, 1.f, 0, 0LL, 0LL, 0, 0, 0);

    ln_kernel<<<NROWS, blk, 0, stream>>>(X2, ln2_g, ln2_b, 0LL, H);

    // FC + proj in 2 row-chunks of 4100; bf16 MID shares T1 (25.2MB <= 33.5MB)
    {
        bf16* MID = (bf16*)T1;
        for (int cidx = 0; cidx < 2; ++cidx) {
            long long r0 = 4100LL * cidx;
            int m = 4100;
            gemm_k<0,0,1,0,0><<<dim3(48, 65, 1), blk, 0, stream>>>(
                H + r0 * CDIM, w_fc, b_fc, nullptr, MID,
                m, 4*CDIM, CDIM, CDIM, 4*CDIM, 4*CDIM, 0, 1.f, 1, 0LL, 0LL, 0, 0, 0);
            gemm_k<0,0,1,1,0><<<dim3(12, 65, 1), blk, 0, stream>>>(
                MID, w_proj, b_proj, nullptr, FFN + r0 * CDIM,
                m, CDIM, 4*CDIM, 4*CDIM, CDIM, CDIM, 0, 1.f, 0, 0LL, 0LL, 0, 0, 0);
        }
    }

    adp_down_kernel<<<NROWS, blk, 0, stream>>>(FFN, w_down, b_down, ADP);
    final_up_kernel<<<NROWS, blk, 0, stream>>>(ADP, w_up, b_up, X2, FFN, out, FEAT);

    // ---- stage B: cluster pooling + BN-GELU ----
    seg_kernel<<<NCLUST, blk, 0, stream>>>(FEAT, cluster, Y512);
    bn_gelu_kernel<<<CDIM, dim3(128), 0, stream>>>(Y512, bn3d_g, bn3d_b, 0LL, BN3D, NCLUST);

    // ---- stage C: 6 views ----
    const float inv_sqrt_c = 0.03608439182435161f; // 1/sqrt(768)
    for (int i = 0; i < NVIEW; ++i) {
        ln_kernel<<<NFEAT, blk, 0, stream>>>(FEAT, n3_g, n3_b, (long long)i * CDIM, H);

        gemm_k<0,0,1,0,0><<<dim3(36, 128, 1), blk, 0, stream>>>(
            H, vw_qkv, vb_qkv, nullptr, QKV,
            NFEAT, 3*CDIM, CDIM, CDIM, 3*CDIM, 3*CDIM, 0, 1.f, 0,
            (long long)i * CDIM * 3*CDIM, (long long)i * 3*CDIM, 0, 0, 0);

        // scores = q1 @ k1^T / sqrt(C) (f32 out, batched over 8)
        gemm_k<1,0,0,1,0><<<dim3(16, 16, BATCH), blk, 0, stream>>>(
            QKV, QKV + CDIM, nullptr, nullptr, T1,
            GTOK, GTOK, CDIM, 3*CDIM, 3*CDIM, GTOK, 0, inv_sqrt_c, 0, 0LL, 0LL,
            (long long)GTOK * 3*CDIM, (long long)GTOK * 3*CDIM, (long long)GTOK * GTOK);

        softmax_rows<<<BATCH * GTOK, blk, 0, stream>>>(T1);

        // o1 = a1 @ v1 (A f32, batched over 8) -> AO (bf16)
        gemm_k<0,1,0,0,0><<<dim3(12, 16, BATCH), blk, 0, stream>>>(
            T1, QKV + 2*CDIM, nullptr, nullptr, AO,
            GTOK, CDIM, GTOK, GTOK, 3*CDIM, CDIM, 0, 1.f, 0, 0LL, 0LL,
            (long long)GTOK * GTOK, (long long)GTOK * 3*CDIM, (long long)GTOK * CDIM);

        // fx = o1 @ vw_o + vb_o + feat -> X2 (f32)
        gemm_k<0,0,1,1,1><<<dim3(12, 128, 1), blk, 0, stream>>>(
            AO, vw_o, vb_o, FEAT, X2,
            NFEAT, CDIM, CDIM, CDIM, CDIM, CDIM, CDIM, 1.f, 0,
            (long long)i * CDIM * CDIM, (long long)i * CDIM, 0, 0, 0);

        seg_kernel<<<NGRID, blk, 0, stream>>>(X2, fgi + i * NFEAT, YG);
        bn_gelu_kernel<<<CDIM, dim3(128), 0, stream>>>(
            YG, bn1d_g, bn1d_b, (long long)i * CDIM,
            BN1D + (long long)i * NGRID * CDIM, NGRID);
    }

    // ---- final fusion ----
    fuse_final_kernel<<<NFEAT, blk, 0, stream>>>(FEAT, BN3D, BN1D, cluster, fgi, out);
}

// Round 10
// 11655.128 us; speedup vs baseline: 1.9241x; 1.4463x over previous
//
#include <hip/hip_runtime.h>
#include <math.h>
#include <float.h>

#define BATCH   8
#define SEQ     1025
#define GTOK    1024
#define CDIM    768
#define NHEAD   12
#define DHEAD   64
#define NVIEW   6
#define NCLUST  512
#define NGRID   1568
#define NROWS   8200
#define NFEAT   8192

typedef unsigned short bf16;
typedef __attribute__((ext_vector_type(8))) short bf16x8;
typedef __attribute__((ext_vector_type(4))) float f32x4;

__device__ __forceinline__ float b2f(bf16 u) {
    union { unsigned int i; float f; } v; v.i = ((unsigned int)u) << 16; return v.f;
}
__device__ __forceinline__ bf16 f2b(float f) {
    union { float f; unsigned int i; } v; v.f = f;
    unsigned int x = v.i;
    return (bf16)((x + 0x7fffu + ((x >> 16) & 1u)) >> 16);
}

__device__ __forceinline__ float block_reduce_sum(float v, float* red) {
    int tid = threadIdx.x;
    red[tid] = v; __syncthreads();
    for (int s = blockDim.x >> 1; s > 0; s >>= 1) {
        if (tid < s) red[tid] += red[tid + s];
        __syncthreads();
    }
    float r = red[0]; __syncthreads();
    return r;
}

__device__ __forceinline__ float gelu_exact(float v) {
    return 0.5f * v * (1.f + erff(v * 0.70710678118654752f));
}
__device__ __forceinline__ float quick_gelu(float v) {
    return v / (1.f + expf(-1.702f * v));
}

// ---------------------------------------------------------------------------
// LayerNorm: one block per row (f32 input, f32 gamma/beta, bf16 out)
// ---------------------------------------------------------------------------
__global__ __launch_bounds__(256)
void ln_kernel(const float* __restrict__ x, const float* __restrict__ g,
               const float* __restrict__ b, long long goff, bf16* __restrict__ out)
{
    __shared__ float red[256];
    long long row = blockIdx.x;
    int tid = threadIdx.x;
    long long base = row * CDIM;
    float v0 = x[base + tid], v1 = x[base + tid + 256], v2 = x[base + tid + 512];
    float mean = block_reduce_sum(v0 + v1 + v2, red) * (1.f / CDIM);
    float d0 = v0 - mean, d1 = v1 - mean, d2 = v2 - mean;
    float var = block_reduce_sum(d0 * d0 + d1 * d1 + d2 * d2, red) * (1.f / CDIM);
    float rstd = rsqrtf(var + 1e-5f);
    bf16* orow = out + base;
    orow[tid]       = f2b(d0 * rstd * g[goff + tid]       + b[goff + tid]);
    orow[tid + 256] = f2b(d1 * rstd * g[goff + tid + 256] + b[goff + tid + 256]);
    orow[tid + 512] = f2b(d2 * rstd * g[goff + tid + 512] + b[goff + tid + 512]);
}

// ---------------------------------------------------------------------------
// MFMA bf16 GEMM: C = act(alpha*A@B(^T) + bias) + Res  (same as round 9)
// ---------------------------------------------------------------------------
#define LDSK 40

template<int TRANSB, int ATY, int BSRC, int OTY, int RES>
__global__ __launch_bounds__(256)
void gemm_k(const void* __restrict__ Av, const void* __restrict__ B,
            const void* __restrict__ bias, const float* __restrict__ Res,
            void* __restrict__ Cv,
            int M, int N, int K, int lda, int ldb, int ldc, int ldres,
            float alpha, int act, long long boff, long long biasoff,
            long long sA, long long sB, long long sC)
{
    __shared__ short As[64][LDSK];
    __shared__ short Bs[64][LDSK];
    int bz = blockIdx.z;
    int tid = threadIdx.x;
    int m0 = blockIdx.y * 64, n0 = blockIdx.x * 64;
    long long Aoff = (long long)bz * sA;
    long long Boff = boff + (long long)bz * sB;

    int lane = tid & 63;
    int w = tid >> 6;
    int wr = w >> 1, wc = w & 1;
    int fr = lane & 15;
    int kg = lane >> 4;

    f32x4 acc[2][2] = {};

    for (int k0 = 0; k0 < K; k0 += 32) {
        {
            int r = tid >> 2, kb = (tid & 3) * 8;
            int gm = m0 + r;
            short tmp[8] = {};
            if (gm < M) {
                long long base = Aoff + (long long)gm * lda + k0 + kb;
                if (k0 + kb + 8 <= K) {
                    if (ATY == 0) {
                        *reinterpret_cast<uint4*>(tmp) =
                            *reinterpret_cast<const uint4*>((const bf16*)Av + base);
                    } else {
                        float4 f0 = *reinterpret_cast<const float4*>((const float*)Av + base);
                        float4 f1 = *reinterpret_cast<const float4*>((const float*)Av + base + 4);
                        tmp[0]=(short)f2b(f0.x); tmp[1]=(short)f2b(f0.y);
                        tmp[2]=(short)f2b(f0.z); tmp[3]=(short)f2b(f0.w);
                        tmp[4]=(short)f2b(f1.x); tmp[5]=(short)f2b(f1.y);
                        tmp[6]=(short)f2b(f1.z); tmp[7]=(short)f2b(f1.w);
                    }
                } else {
                    #pragma unroll
                    for (int j = 0; j < 8; ++j) {
                        if (k0 + kb + j < K)
                            tmp[j] = ATY ? (short)f2b(((const float*)Av)[base + j])
                                         : (short)((const bf16*)Av)[base + j];
                    }
                }
            }
            *reinterpret_cast<uint4*>(&As[r][kb]) = *reinterpret_cast<uint4*>(tmp);
        }
        {
            int col = tid >> 2, kb = (tid & 3) * 8;
            int gn = n0 + col;
            short tmp[8] = {};
            if (gn < N) {
                if (TRANSB) {
                    long long base = Boff + (long long)gn * ldb + k0 + kb;
                    if (k0 + kb + 8 <= K) {
                        if (BSRC == 0) {
                            *reinterpret_cast<uint4*>(tmp) =
                                *reinterpret_cast<const uint4*>((const bf16*)B + base);
                        } else {
                            float4 f0 = *reinterpret_cast<const float4*>((const float*)B + base);
                            float4 f1 = *reinterpret_cast<const float4*>((const float*)B + base + 4);
                            tmp[0]=(short)f2b(f0.x); tmp[1]=(short)f2b(f0.y);
                            tmp[2]=(short)f2b(f0.z); tmp[3]=(short)f2b(f0.w);
                            tmp[4]=(short)f2b(f1.x); tmp[5]=(short)f2b(f1.y);
                            tmp[6]=(short)f2b(f1.z); tmp[7]=(short)f2b(f1.w);
                        }
                    } else {
                        #pragma unroll
                        for (int j = 0; j < 8; ++j) {
                            if (k0 + kb + j < K)
                                tmp[j] = BSRC ? (short)f2b(((const float*)B)[base + j])
                                              : (short)((const bf16*)B)[base + j];
                        }
                    }
                } else {
                    #pragma unroll
                    for (int j = 0; j < 8; ++j) {
                        int kk = k0 + kb + j;
                        if (kk < K) {
                            long long bi = Boff + (long long)kk * ldb + gn;
                            tmp[j] = BSRC ? (short)f2b(((const float*)B)[bi])
                                          : (short)((const bf16*)B)[bi];
                        }
                    }
                }
            }
            *reinterpret_cast<uint4*>(&Bs[col][kb]) = *reinterpret_cast<uint4*>(tmp);
        }
        __syncthreads();

        bf16x8 a0 = *reinterpret_cast<const bf16x8*>(&As[wr * 32 + fr][kg * 8]);
        bf16x8 a1 = *reinterpret_cast<const bf16x8*>(&As[wr * 32 + 16 + fr][kg * 8]);
        bf16x8 b0 = *reinterpret_cast<const bf16x8*>(&Bs[wc * 32 + fr][kg * 8]);
        bf16x8 b1 = *reinterpret_cast<const bf16x8*>(&Bs[wc * 32 + 16 + fr][kg * 8]);
        acc[0][0] = __builtin_amdgcn_mfma_f32_16x16x32_bf16(a0, b0, acc[0][0], 0, 0, 0);
        acc[0][1] = __builtin_amdgcn_mfma_f32_16x16x32_bf16(a0, b1, acc[0][1], 0, 0, 0);
        acc[1][0] = __builtin_amdgcn_mfma_f32_16x16x32_bf16(a1, b0, acc[1][0], 0, 0, 0);
        acc[1][1] = __builtin_amdgcn_mfma_f32_16x16x32_bf16(a1, b1, acc[1][1], 0, 0, 0);
        __syncthreads();
    }

    #pragma unroll
    for (int m = 0; m < 2; ++m) {
        #pragma unroll
        for (int n = 0; n < 2; ++n) {
            #pragma unroll
            for (int i = 0; i < 4; ++i) {
                int gm = m0 + wr * 32 + m * 16 + kg * 4 + i;
                int gn = n0 + wc * 32 + n * 16 + fr;
                if (gm >= M || gn >= N) continue;
                float v = acc[m][n][i] * alpha;
                if (bias) v += BSRC ? ((const float*)bias)[biasoff + gn]
                                    : b2f(((const bf16*)bias)[biasoff + gn]);
                if (act == 1) v = quick_gelu(v);
                if (RES) v += Res[(long long)gm * ldres + gn];
                long long ci = sC * bz + (long long)gm * ldc + gn;
                if (OTY) ((float*)Cv)[ci] = v;
                else     ((bf16*)Cv)[ci] = f2b(v);
            }
        }
    }
}

// ---------------------------------------------------------------------------
// Fused softmax + attn_weight accumulate for main attention.
// One block per (b,q) row. T1 row (width SEQ, f32) -> probs in place;
// aw (+)= p/NHEAD in d_out at offset NROWS*CDIM. first=1: write, else add.
// ---------------------------------------------------------------------------
__global__ __launch_bounds__(256)
void softmax_aw_kernel(float* __restrict__ T1, float* __restrict__ out, int first)
{
    __shared__ float red[256];
    long long r = blockIdx.x;              // 0..NROWS-1 == b*SEQ+q
    float* sr = T1 + r * SEQ;
    float* aw = out + (long long)NROWS * CDIM + r * SEQ;
    int tid = threadIdx.x;

    float lmax = -FLT_MAX;
    for (int k = tid; k < SEQ; k += 256) lmax = fmaxf(lmax, sr[k]);
    red[tid] = lmax; __syncthreads();
    for (int st = 128; st > 0; st >>= 1) {
        if (tid < st) red[tid] = fmaxf(red[tid], red[tid + st]);
        __syncthreads();
    }
    float m = red[0]; __syncthreads();

    float ls = 0.f;
    for (int k = tid; k < SEQ; k += 256) {
        float p = expf(sr[k] - m);
        sr[k] = p; ls += p;
    }
    float Z = block_reduce_sum(ls, red);
    float inv = 1.f / fmaxf(Z, 1e-30f);
    const float hscale = 1.f / (float)NHEAD;
    for (int k = tid; k < SEQ; k += 256) {
        float p = sr[k] * inv;
        sr[k] = p;
        aw[k] = (first ? 0.f : aw[k]) + p * hscale;
    }
}

// ---------------------------------------------------------------------------
// Row softmax on f32 rows of width 1024, in place (view attention)
// ---------------------------------------------------------------------------
__global__ __launch_bounds__(256)
void softmax_rows(float* __restrict__ s)
{
    __shared__ float red[256];
    long long row = blockIdx.x;
    float* sr = s + row * GTOK;
    int tid = threadIdx.x;
    float v[4];
    float lmax = -FLT_MAX;
    #pragma unroll
    for (int i = 0; i < 4; ++i) { v[i] = sr[tid + i * 256]; lmax = fmaxf(lmax, v[i]); }
    red[tid] = lmax; __syncthreads();
    for (int st = 128; st > 0; st >>= 1) {
        if (tid < st) red[tid] = fmaxf(red[tid], red[tid + st]);
        __syncthreads();
    }
    float m = red[0]; __syncthreads();
    float ls = 0.f;
    #pragma unroll
    for (int i = 0; i < 4; ++i) { v[i] = expf(v[i] - m); ls += v[i]; }
    float Z = block_reduce_sum(ls, red);
    float inv = 1.f / fmaxf(Z, 1e-30f);
    #pragma unroll
    for (int i = 0; i < 4; ++i) sr[tid + i * 256] = v[i] * inv;
}

// ---------------------------------------------------------------------------
// adapter down: adp1 = gelu(ffn @ w_down + b_down) -> f32 (NROWS,16)
// ---------------------------------------------------------------------------
__global__ __launch_bounds__(256)
void adp_down_kernel(const float* __restrict__ ffn, const float* __restrict__ w,
                     const float* __restrict__ bias, float* __restrict__ out)
{
    __shared__ float rowsh[CDIM];
    __shared__ float red[256];
    long long row = blockIdx.x;
    int tid = threadIdx.x;
    for (int c = tid; c < CDIM; c += 256) rowsh[c] = ffn[row * CDIM + c];
    __syncthreads();
    int n = tid >> 4;
    int part = tid & 15;
    float s = 0.f;
    for (int i = part; i < CDIM; i += 16) s += rowsh[i] * w[i * 16 + n];
    red[tid] = s; __syncthreads();
    if (part == 0) {
        float t = 0.f;
        #pragma unroll
        for (int p = 0; p < 16; ++p) t += red[n * 16 + p];
        t += bias[n];
        out[row * 16 + n] = gelu_exact(t);
    }
}

// ---------------------------------------------------------------------------
// final up + residuals: v = x2 + ffn + 0.5*(adp1 @ w_up + b_up)   (f32)
// ---------------------------------------------------------------------------
__global__ __launch_bounds__(256)
void final_up_kernel(const float* __restrict__ adp1, const float* __restrict__ w_up,
                     const float* __restrict__ b_up, const float* __restrict__ x2,
                     const float* __restrict__ ffn, float* __restrict__ out,
                     float* __restrict__ feat)
{
    __shared__ float a[16];
    long long row = blockIdx.x;
    int tid = threadIdx.x;
    if (tid < 16) a[tid] = adp1[row * 16 + tid];
    __syncthreads();
    int b = (int)(row / SEQ);
    int s = (int)(row % SEQ);
    #pragma unroll
    for (int i = 0; i < 3; ++i) {
        int c = tid + i * 256;
        float acc = b_up[c];
        #pragma unroll
        for (int k = 0; k < 16; ++k) acc += a[k] * w_up[k * CDIM + c];
        float v = x2[row * CDIM + c] + ffn[row * CDIM + c] + 0.5f * acc;
        out[row * CDIM + c] = v;
        if (s > 0)
            feat[((long long)b * GTOK + (s - 1)) * CDIM + c] = v;
    }
}

// ---------------------------------------------------------------------------
// Deterministic segment max+mean over 8192 f32 rows; y = mx + mn (f32)
// ---------------------------------------------------------------------------
__global__ __launch_bounds__(256)
void seg_kernel(const float* __restrict__ feat, const int* __restrict__ idx,
                float* __restrict__ y)
{
    __shared__ int sidx[NFEAT];
    int seg = blockIdx.x;
    int tid = threadIdx.x;
    for (int j = tid; j < NFEAT; j += 256) sidx[j] = idx[j];
    __syncthreads();
    float mx0 = -FLT_MAX, mx1 = -FLT_MAX, mx2 = -FLT_MAX;
    float s0 = 0.f, s1 = 0.f, s2 = 0.f;
    int cnt = 0;
    for (int j = 0; j < NFEAT; ++j) {
        if (sidx[j] == seg) {
            const float* fr = feat + (long long)j * CDIM;
            float v0 = fr[tid], v1 = fr[tid + 256], v2 = fr[tid + 512];
            s0 += v0; s1 += v1; s2 += v2;
            mx0 = fmaxf(mx0, v0); mx1 = fmaxf(mx1, v1); mx2 = fmaxf(mx2, v2);
            ++cnt;
        }
    }
    if (cnt == 0) { mx0 = mx1 = mx2 = 0.f; }
    float inv = 1.f / (float)(cnt > 0 ? cnt : 1);
    float* yr = y + (long long)seg * CDIM;
    yr[tid]       = mx0 + s0 * inv;
    yr[tid + 256] = mx1 + s1 * inv;
    yr[tid + 512] = mx2 + s2 * inv;
}

// ---------------------------------------------------------------------------
// BatchNorm over rows (two-pass) + exact GELU -> bf16
// ---------------------------------------------------------------------------
__global__ __launch_bounds__(128)
void bn_gelu_kernel(const float* __restrict__ y, const float* __restrict__ g,
                    const float* __restrict__ b, long long goff,
                    bf16* __restrict__ out, int R)
{
    __shared__ float red[128];
    int c = blockIdx.x;
    int tid = threadIdx.x;
    float s = 0.f;
    for (int r = tid; r < R; r += 128) s += y[(long long)r * CDIM + c];
    float mean = block_reduce_sum(s, red) / (float)R;
    float ss = 0.f;
    for (int r = tid; r < R; r += 128) {
        float d = y[(long long)r * CDIM + c] - mean;
        ss += d * d;
    }
    float var = fmaxf(block_reduce_sum(ss, red) / (float)R, 0.f);
    float rstd = rsqrtf(var + 1e-5f);
    float gc = g[goff + c], bc = b[goff + c];
    for (int r = tid; r < R; r += 128) {
        float v = (y[(long long)r * CDIM + c] - mean) * rstd * gc + bc;
        out[(long long)r * CDIM + c] = f2b(gelu_exact(v));
    }
}

// ---------------------------------------------------------------------------
// Final fusion: cosine sims over 6 views, weighted sum, write f32 out rows
// ---------------------------------------------------------------------------
__global__ __launch_bounds__(256)
void fuse_final_kernel(const float* __restrict__ feat, const bf16* __restrict__ bn3d,
                       const bf16* __restrict__ bn1d, const int* __restrict__ cluster,
                       const int* __restrict__ fgi, float* __restrict__ out)
{
    __shared__ float red[256];
    __shared__ float simsh[NVIEW];
    int j = blockIdx.x;
    int tid = threadIdx.x;
    int b = j >> 10, g = j & 1023;
    const bf16* x3 = bn3d + (long long)cluster[j] * CDIM;
    float s = 0.f;
    for (int c = tid; c < CDIM; c += 256) { float v = b2f(x3[c]); s += v * v; }
    float nx3 = fmaxf(sqrtf(block_reduce_sum(s, red)), 1e-8f);

    for (int i = 0; i < NVIEW; ++i) {
        const bf16* p = bn1d + ((long long)i * NGRID + fgi[i * NFEAT + j]) * CDIM;
        float d = 0.f, nn = 0.f;
        for (int c = tid; c < CDIM; c += 256) {
            float pv = b2f(p[c]);
            d += pv * b2f(x3[c]); nn += pv * pv;
        }
        float D = block_reduce_sum(d, red);
        float Np = sqrtf(block_reduce_sum(nn, red));
        if (tid == 0) {
            float cosv = D / (fmaxf(Np, 1e-8f) * nx3);
            simsh[i] = (cosv + 1.f) * 0.5f;
        }
        __syncthreads();
    }
    float ssum = 0.f;
    #pragma unroll
    for (int i = 0; i < NVIEW; ++i) ssum += simsh[i];
    float invs = 1.f / fmaxf(ssum, 1e-20f);
    long long orow = ((long long)b * SEQ + 1 + g) * CDIM;
    for (int c = tid; c < CDIM; c += 256) {
        float acc = 0.f;
        #pragma unroll
        for (int i = 0; i < NVIEW; ++i) {
            const bf16* p = bn1d + ((long long)i * NGRID + fgi[i * NFEAT + j]) * CDIM;
            acc += simsh[i] * invs * b2f(p[c]);
        }
        out[orow + c] = feat[(long long)j * CDIM + c] + 0.3f * acc;
    }
}

// ---------------------------------------------------------------------------
// Host side
// ---------------------------------------------------------------------------
extern "C" void kernel_launch(void* const* d_in, const int* in_sizes, int n_in,
                              void* d_out, int out_size, void* d_ws, size_t ws_size,
                              hipStream_t stream)
{
    const float* x      = (const float*)d_in[0];
    const int*  cluster = (const int*)d_in[2];
    const int*  fgi     = (const int*)d_in[3];
    const float* ln1_g = (const float*)d_in[6];
    const float* ln1_b = (const float*)d_in[7];
    const float* w_qkv = (const float*)d_in[8];
    const float* b_qkv = (const float*)d_in[9];
    const float* w_o   = (const float*)d_in[10];
    const float* b_o   = (const float*)d_in[11];
    const float* ln2_g = (const float*)d_in[12];
    const float* ln2_b = (const float*)d_in[13];
    const float* w_fc  = (const float*)d_in[14];
    const float* b_fc  = (const float*)d_in[15];
    const float* w_proj= (const float*)d_in[16];
    const float* b_proj= (const float*)d_in[17];
    const float* w_down= (const float*)d_in[18];
    const float* b_down= (const float*)d_in[19];
    const float* w_up  = (const float*)d_in[20];
    const float* b_up  = (const float*)d_in[21];
    const float* bn3d_g= (const float*)d_in[22];
    const float* bn3d_b= (const float*)d_in[23];
    const float* n3_g  = (const float*)d_in[24];
    const float* n3_b  = (const float*)d_in[25];
    const float* vw_qkv= (const float*)d_in[26];
    const float* vb_qkv= (const float*)d_in[27];
    const float* vw_o  = (const float*)d_in[28];
    const float* vb_o  = (const float*)d_in[29];
    const float* bn1d_g= (const float*)d_in[30];
    const float* bn1d_b= (const float*)d_in[31];
    (void)in_sizes; (void)n_in; (void)out_size; (void)ws_size;

    float* out = (float*)d_out;

    // workspace layout (bytes), total ~185.1 MB
    char* w = (char*)d_ws;
    bf16*  QKV  = (bf16*)w;  w += (long long)NROWS * 3 * CDIM * 2;    // 37.8 MB
    bf16*  H    = (bf16*)w;  w += (long long)NROWS * CDIM * 2;        // 12.6 MB
    float* X2   = (float*)w; w += (long long)NROWS * CDIM * 4;        // 25.2 MB
    bf16*  AO   = (bf16*)w;  w += (long long)NROWS * CDIM * 2;        // 12.6 MB
    float* FFN  = (float*)w; w += (long long)NROWS * CDIM * 4;        // 25.2 MB
    float* T1   = (float*)w; w += (long long)BATCH * SEQ * SEQ * 4;   // 33.6 MB (SEQ^2!)
    float* ADP  = (float*)w; w += (long long)NROWS * 16 * 4;          // 0.5 MB
    float* FEAT = (float*)w; w += (long long)NFEAT * CDIM * 4;        // 25.2 MB
    float* Y512 = (float*)w; w += (long long)NCLUST * CDIM * 4;       // 1.6 MB
    bf16*  BN3D = (bf16*)w;  w += (long long)NCLUST * CDIM * 2;       // 0.8 MB
    float* YG   = (float*)w; w += (long long)NGRID * CDIM * 4;        // 4.8 MB
    bf16*  BN1D = (bf16*)w;  w += (long long)NVIEW * NGRID * CDIM * 2;// 14.5 MB

    dim3 blk(256);

    // ---- stage A: transformer block ----
    ln_kernel<<<NROWS, blk, 0, stream>>>(x, ln1_g, ln1_b, 0LL, H);

    gemm_k<0,0,1,0,0><<<dim3(36, 129, 1), blk, 0, stream>>>(
        H, w_qkv, b_qkv, nullptr, QKV,
        NROWS, 3*CDIM, CDIM, CDIM, 3*CDIM, 3*CDIM, 0, 1.f, 0, 0LL, 0LL, 0, 0, 0);

    // ---- main attention via per-head MFMA GEMMs ----
    for (int h = 0; h < NHEAD; ++h) {
        // scores = Q_h @ K_h^T / sqrt(64) -> T1 (f32, 8 x SEQ x SEQ)
        gemm_k<1,0,0,1,0><<<dim3(17, 17, BATCH), blk, 0, stream>>>(
            QKV + h * DHEAD, QKV + CDIM + h * DHEAD, nullptr, nullptr, T1,
            SEQ, SEQ, DHEAD, 3*CDIM, 3*CDIM, SEQ, 0, 0.125f, 0, 0LL, 0LL,
            (long long)SEQ * 3*CDIM, (long long)SEQ * 3*CDIM, (long long)SEQ * SEQ);

        // softmax rows + attn_weight accumulate
        softmax_aw_kernel<<<NROWS, blk, 0, stream>>>(T1, out, h == 0 ? 1 : 0);

        // O_h = P @ V_h -> AO columns [h*64 .. h*64+63]
        gemm_k<0,1,0,0,0><<<dim3(1, 17, BATCH), blk, 0, stream>>>(
            T1, QKV + 2*CDIM + h * DHEAD, nullptr, nullptr, AO + h * DHEAD,
            SEQ, DHEAD, SEQ, SEQ, 3*CDIM, CDIM, 0, 1.f, 0, 0LL, 0LL,
            (long long)SEQ * SEQ, (long long)SEQ * 3*CDIM, (long long)SEQ * CDIM);
    }

    // x2 = AO @ w_o + b_o + x   -> f32
    gemm_k<0,0,1,1,1><<<dim3(12, 129, 1), blk, 0, stream>>>(
        AO, w_o, b_o, x, X2,
        NROWS, CDIM, CDIM, CDIM, CDIM, CDIM, CDIM, 1.f, 0, 0LL, 0LL, 0, 0, 0);

    ln_kernel<<<NROWS, blk, 0, stream>>>(X2, ln2_g, ln2_b, 0LL, H);

    // FC + proj in 2 row-chunks of 4100; bf16 MID shares T1 (25.2MB <= 33.6MB)
    {
        bf16* MID = (bf16*)T1;
        for (int cidx = 0; cidx < 2; ++cidx) {
            long long r0 = 4100LL * cidx;
            int m = 4100;
            gemm_k<0,0,1,0,0><<<dim3(48, 65, 1), blk, 0, stream>>>(
                H + r0 * CDIM, w_fc, b_fc, nullptr, MID,
                m, 4*CDIM, CDIM, CDIM, 4*CDIM, 4*CDIM, 0, 1.f, 1, 0LL, 0LL, 0, 0, 0);
            gemm_k<0,0,1,1,0><<<dim3(12, 65, 1), blk, 0, stream>>>(
                MID, w_proj, b_proj, nullptr, FFN + r0 * CDIM,
                m, CDIM, 4*CDIM, 4*CDIM, CDIM, CDIM, 0, 1.f, 0, 0LL, 0LL, 0, 0, 0);
        }
    }

    adp_down_kernel<<<NROWS, blk, 0, stream>>>(FFN, w_down, b_down, ADP);
    final_up_kernel<<<NROWS, blk, 0, stream>>>(ADP, w_up, b_up, X2, FFN, out, FEAT);

    // ---- stage B: cluster pooling + BN-GELU ----
    seg_kernel<<<NCLUST, blk, 0, stream>>>(FEAT, cluster, Y512);
    bn_gelu_kernel<<<CDIM, dim3(128), 0, stream>>>(Y512, bn3d_g, bn3d_b, 0LL, BN3D, NCLUST);

    // ---- stage C: 6 views ----
    const float inv_sqrt_c = 0.03608439182435161f; // 1/sqrt(768)
    for (int i = 0; i < NVIEW; ++i) {
        ln_kernel<<<NFEAT, blk, 0, stream>>>(FEAT, n3_g, n3_b, (long long)i * CDIM, H);

        gemm_k<0,0,1,0,0><<<dim3(36, 128, 1), blk, 0, stream>>>(
            H, vw_qkv, vb_qkv, nullptr, QKV,
            NFEAT, 3*CDIM, CDIM, CDIM, 3*CDIM, 3*CDIM, 0, 1.f, 0,
            (long long)i * CDIM * 3*CDIM, (long long)i * 3*CDIM, 0, 0, 0);

        // scores = q1 @ k1^T / sqrt(C) (f32 out, batched over 8)
        gemm_k<1,0,0,1,0><<<dim3(16, 16, BATCH), blk, 0, stream>>>(
            QKV, QKV + CDIM, nullptr, nullptr, T1,
            GTOK, GTOK, CDIM, 3*CDIM, 3*CDIM, GTOK, 0, inv_sqrt_c, 0, 0LL, 0LL,
            (long long)GTOK * 3*CDIM, (long long)GTOK * 3*CDIM, (long long)GTOK * GTOK);

        softmax_rows<<<BATCH * GTOK, blk, 0, stream>>>(T1);

        // o1 = a1 @ v1 (A f32, batched over 8) -> AO (bf16)
        gemm_k<0,1,0,0,0><<<dim3(12, 16, BATCH), blk, 0, stream>>>(
            T1, QKV + 2*CDIM, nullptr, nullptr, AO,
            GTOK, CDIM, GTOK, GTOK, 3*CDIM, CDIM, 0, 1.f, 0, 0LL, 0LL,
            (long long)GTOK * GTOK, (long long)GTOK * 3*CDIM, (long long)GTOK * CDIM);

        // fx = o1 @ vw_o + vb_o + feat -> X2 (f32)
        gemm_k<0,0,1,1,1><<<dim3(12, 128, 1), blk, 0, stream>>>(
            AO, vw_o, vb_o, FEAT, X2,
            NFEAT, CDIM, CDIM, CDIM, CDIM, CDIM, CDIM, 1.f, 0,
            (long long)i * CDIM * CDIM, (long long)i * CDIM, 0, 0, 0);

        seg_kernel<<<NGRID, blk, 0, stream>>>(X2, fgi + i * NFEAT, YG);
        bn_gelu_kernel<<<CDIM, dim3(128), 0, stream>>>(
            YG, bn1d_g, bn1d_b, (long long)i * CDIM,
            BN1D + (long long)i * NGRID * CDIM, NGRID);
    }

    // ---- final fusion ----
    fuse_final_kernel<<<NFEAT, blk, 0, stream>>>(FEAT, BN3D, BN1D, cluster, fgi, out);
}

// Round 11
// 6678.763 us; speedup vs baseline: 3.3577x; 1.7451x over previous
//
#include <hip/hip_runtime.h>
#include <math.h>
#include <float.h>

#define BATCH   8
#define SEQ     1025
#define GTOK    1024
#define CDIM    768
#define NHEAD   12
#define DHEAD   64
#define NVIEW   6
#define NCLUST  512
#define NGRID   1568
#define NROWS   8200
#define NFEAT   8192
#define SEGCAP  2048

typedef unsigned short bf16;
typedef __attribute__((ext_vector_type(8))) short bf16x8;
typedef __attribute__((ext_vector_type(4))) float f32x4;

__device__ __forceinline__ float b2f(bf16 u) {
    union { unsigned int i; float f; } v; v.i = ((unsigned int)u) << 16; return v.f;
}
__device__ __forceinline__ bf16 f2b(float f) {
    union { float f; unsigned int i; } v; v.f = f;
    unsigned int x = v.i;
    return (bf16)((x + 0x7fffu + ((x >> 16) & 1u)) >> 16);
}

__device__ __forceinline__ float block_reduce_sum(float v, float* red) {
    int tid = threadIdx.x;
    red[tid] = v; __syncthreads();
    for (int s = blockDim.x >> 1; s > 0; s >>= 1) {
        if (tid < s) red[tid] += red[tid + s];
        __syncthreads();
    }
    float r = red[0]; __syncthreads();
    return r;
}

__device__ __forceinline__ float gelu_exact(float v) {
    return 0.5f * v * (1.f + erff(v * 0.70710678118654752f));
}
__device__ __forceinline__ float quick_gelu(float v) {
    return v / (1.f + expf(-1.702f * v));
}

// ---------------------------------------------------------------------------
// LayerNorm: one block per row (f32 input, f32 gamma/beta, bf16 out)
// ---------------------------------------------------------------------------
__global__ __launch_bounds__(256)
void ln_kernel(const float* __restrict__ x, const float* __restrict__ g,
               const float* __restrict__ b, long long goff, bf16* __restrict__ out)
{
    __shared__ float red[256];
    long long row = blockIdx.x;
    int tid = threadIdx.x;
    long long base = row * CDIM;
    float v0 = x[base + tid], v1 = x[base + tid + 256], v2 = x[base + tid + 512];
    float mean = block_reduce_sum(v0 + v1 + v2, red) * (1.f / CDIM);
    float d0 = v0 - mean, d1 = v1 - mean, d2 = v2 - mean;
    float var = block_reduce_sum(d0 * d0 + d1 * d1 + d2 * d2, red) * (1.f / CDIM);
    float rstd = rsqrtf(var + 1e-5f);
    bf16* orow = out + base;
    orow[tid]       = f2b(d0 * rstd * g[goff + tid]       + b[goff + tid]);
    orow[tid + 256] = f2b(d1 * rstd * g[goff + tid + 256] + b[goff + tid + 256]);
    orow[tid + 512] = f2b(d2 * rstd * g[goff + tid + 512] + b[goff + tid + 512]);
}

// ---------------------------------------------------------------------------
// MFMA bf16 GEMM: C = act(alpha*A@B(^T) + bias) + Res  (same as round 10)
// ---------------------------------------------------------------------------
#define LDSK 40

template<int TRANSB, int ATY, int BSRC, int OTY, int RES>
__global__ __launch_bounds__(256)
void gemm_k(const void* __restrict__ Av, const void* __restrict__ B,
            const void* __restrict__ bias, const float* __restrict__ Res,
            void* __restrict__ Cv,
            int M, int N, int K, int lda, int ldb, int ldc, int ldres,
            float alpha, int act, long long boff, long long biasoff,
            long long sA, long long sB, long long sC)
{
    __shared__ short As[64][LDSK];
    __shared__ short Bs[64][LDSK];
    int bz = blockIdx.z;
    int tid = threadIdx.x;
    int m0 = blockIdx.y * 64, n0 = blockIdx.x * 64;
    long long Aoff = (long long)bz * sA;
    long long Boff = boff + (long long)bz * sB;

    int lane = tid & 63;
    int w = tid >> 6;
    int wr = w >> 1, wc = w & 1;
    int fr = lane & 15;
    int kg = lane >> 4;

    f32x4 acc[2][2] = {};

    for (int k0 = 0; k0 < K; k0 += 32) {
        {
            int r = tid >> 2, kb = (tid & 3) * 8;
            int gm = m0 + r;
            short tmp[8] = {};
            if (gm < M) {
                long long base = Aoff + (long long)gm * lda + k0 + kb;
                if (k0 + kb + 8 <= K) {
                    if (ATY == 0) {
                        *reinterpret_cast<uint4*>(tmp) =
                            *reinterpret_cast<const uint4*>((const bf16*)Av + base);
                    } else {
                        float4 f0 = *reinterpret_cast<const float4*>((const float*)Av + base);
                        float4 f1 = *reinterpret_cast<const float4*>((const float*)Av + base + 4);
                        tmp[0]=(short)f2b(f0.x); tmp[1]=(short)f2b(f0.y);
                        tmp[2]=(short)f2b(f0.z); tmp[3]=(short)f2b(f0.w);
                        tmp[4]=(short)f2b(f1.x); tmp[5]=(short)f2b(f1.y);
                        tmp[6]=(short)f2b(f1.z); tmp[7]=(short)f2b(f1.w);
                    }
                } else {
                    #pragma unroll
                    for (int j = 0; j < 8; ++j) {
                        if (k0 + kb + j < K)
                            tmp[j] = ATY ? (short)f2b(((const float*)Av)[base + j])
                                         : (short)((const bf16*)Av)[base + j];
                    }
                }
            }
            *reinterpret_cast<uint4*>(&As[r][kb]) = *reinterpret_cast<uint4*>(tmp);
        }
        {
            int col = tid >> 2, kb = (tid & 3) * 8;
            int gn = n0 + col;
            short tmp[8] = {};
            if (gn < N) {
                if (TRANSB) {
                    long long base = Boff + (long long)gn * ldb + k0 + kb;
                    if (k0 + kb + 8 <= K) {
                        if (BSRC == 0) {
                            *reinterpret_cast<uint4*>(tmp) =
                                *reinterpret_cast<const uint4*>((const bf16*)B + base);
                        } else {
                            float4 f0 = *reinterpret_cast<const float4*>((const float*)B + base);
                            float4 f1 = *reinterpret_cast<const float4*>((const float*)B + base + 4);
                            tmp[0]=(short)f2b(f0.x); tmp[1]=(short)f2b(f0.y);
                            tmp[2]=(short)f2b(f0.z); tmp[3]=(short)f2b(f0.w);
                            tmp[4]=(short)f2b(f1.x); tmp[5]=(short)f2b(f1.y);
                            tmp[6]=(short)f2b(f1.z); tmp[7]=(short)f2b(f1.w);
                        }
                    } else {
                        #pragma unroll
                        for (int j = 0; j < 8; ++j) {
                            if (k0 + kb + j < K)
                                tmp[j] = BSRC ? (short)f2b(((const float*)B)[base + j])
                                              : (short)((const bf16*)B)[base + j];
                        }
                    }
                } else {
                    #pragma unroll
                    for (int j = 0; j < 8; ++j) {
                        int kk = k0 + kb + j;
                        if (kk < K) {
                            long long bi = Boff + (long long)kk * ldb + gn;
                            tmp[j] = BSRC ? (short)f2b(((const float*)B)[bi])
                                          : (short)((const bf16*)B)[bi];
                        }
                    }
                }
            }
            *reinterpret_cast<uint4*>(&Bs[col][kb]) = *reinterpret_cast<uint4*>(tmp);
        }
        __syncthreads();

        bf16x8 a0 = *reinterpret_cast<const bf16x8*>(&As[wr * 32 + fr][kg * 8]);
        bf16x8 a1 = *reinterpret_cast<const bf16x8*>(&As[wr * 32 + 16 + fr][kg * 8]);
        bf16x8 b0 = *reinterpret_cast<const bf16x8*>(&Bs[wc * 32 + fr][kg * 8]);
        bf16x8 b1 = *reinterpret_cast<const bf16x8*>(&Bs[wc * 32 + 16 + fr][kg * 8]);
        acc[0][0] = __builtin_amdgcn_mfma_f32_16x16x32_bf16(a0, b0, acc[0][0], 0, 0, 0);
        acc[0][1] = __builtin_amdgcn_mfma_f32_16x16x32_bf16(a0, b1, acc[0][1], 0, 0, 0);
        acc[1][0] = __builtin_amdgcn_mfma_f32_16x16x32_bf16(a1, b0, acc[1][0], 0, 0, 0);
        acc[1][1] = __builtin_amdgcn_mfma_f32_16x16x32_bf16(a1, b1, acc[1][1], 0, 0, 0);
        __syncthreads();
    }

    #pragma unroll
    for (int m = 0; m < 2; ++m) {
        #pragma unroll
        for (int n = 0; n < 2; ++n) {
            #pragma unroll
            for (int i = 0; i < 4; ++i) {
                int gm = m0 + wr * 32 + m * 16 + kg * 4 + i;
                int gn = n0 + wc * 32 + n * 16 + fr;
                if (gm >= M || gn >= N) continue;
                float v = acc[m][n][i] * alpha;
                if (bias) v += BSRC ? ((const float*)bias)[biasoff + gn]
                                    : b2f(((const bf16*)bias)[biasoff + gn]);
                if (act == 1) v = quick_gelu(v);
                if (RES) v += Res[(long long)gm * ldres + gn];
                long long ci = sC * bz + (long long)gm * ldc + gn;
                if (OTY) ((float*)Cv)[ci] = v;
                else     ((bf16*)Cv)[ci] = f2b(v);
            }
        }
    }
}

// ---------------------------------------------------------------------------
// Fused softmax + attn_weight accumulate for main attention.
// ---------------------------------------------------------------------------
__global__ __launch_bounds__(256)
void softmax_aw_kernel(float* __restrict__ T1, float* __restrict__ out, int first)
{
    __shared__ float red[256];
    long long r = blockIdx.x;
    float* sr = T1 + r * SEQ;
    float* aw = out + (long long)NROWS * CDIM + r * SEQ;
    int tid = threadIdx.x;

    float lmax = -FLT_MAX;
    for (int k = tid; k < SEQ; k += 256) lmax = fmaxf(lmax, sr[k]);
    red[tid] = lmax; __syncthreads();
    for (int st = 128; st > 0; st >>= 1) {
        if (tid < st) red[tid] = fmaxf(red[tid], red[tid + st]);
        __syncthreads();
    }
    float m = red[0]; __syncthreads();

    float ls = 0.f;
    for (int k = tid; k < SEQ; k += 256) {
        float p = expf(sr[k] - m);
        sr[k] = p; ls += p;
    }
    float Z = block_reduce_sum(ls, red);
    float inv = 1.f / fmaxf(Z, 1e-30f);
    const float hscale = 1.f / (float)NHEAD;
    for (int k = tid; k < SEQ; k += 256) {
        float p = sr[k] * inv;
        sr[k] = p;
        aw[k] = (first ? 0.f : aw[k]) + p * hscale;
    }
}

// ---------------------------------------------------------------------------
// Row softmax on f32 rows of width 1024, in place (view attention)
// ---------------------------------------------------------------------------
__global__ __launch_bounds__(256)
void softmax_rows(float* __restrict__ s)
{
    __shared__ float red[256];
    long long row = blockIdx.x;
    float* sr = s + row * GTOK;
    int tid = threadIdx.x;
    float v[4];
    float lmax = -FLT_MAX;
    #pragma unroll
    for (int i = 0; i < 4; ++i) { v[i] = sr[tid + i * 256]; lmax = fmaxf(lmax, v[i]); }
    red[tid] = lmax; __syncthreads();
    for (int st = 128; st > 0; st >>= 1) {
        if (tid < st) red[tid] = fmaxf(red[tid], red[tid + st]);
        __syncthreads();
    }
    float m = red[0]; __syncthreads();
    float ls = 0.f;
    #pragma unroll
    for (int i = 0; i < 4; ++i) { v[i] = expf(v[i] - m); ls += v[i]; }
    float Z = block_reduce_sum(ls, red);
    float inv = 1.f / fmaxf(Z, 1e-30f);
    #pragma unroll
    for (int i = 0; i < 4; ++i) sr[tid + i * 256] = v[i] * inv;
}

// ---------------------------------------------------------------------------
// adapter down: adp1 = gelu(ffn @ w_down + b_down) -> f32 (NROWS,16)
// ---------------------------------------------------------------------------
__global__ __launch_bounds__(256)
void adp_down_kernel(const float* __restrict__ ffn, const float* __restrict__ w,
                     const float* __restrict__ bias, float* __restrict__ out)
{
    __shared__ float rowsh[CDIM];
    __shared__ float red[256];
    long long row = blockIdx.x;
    int tid = threadIdx.x;
    for (int c = tid; c < CDIM; c += 256) rowsh[c] = ffn[row * CDIM + c];
    __syncthreads();
    int n = tid >> 4;
    int part = tid & 15;
    float s = 0.f;
    for (int i = part; i < CDIM; i += 16) s += rowsh[i] * w[i * 16 + n];
    red[tid] = s; __syncthreads();
    if (part == 0) {
        float t = 0.f;
        #pragma unroll
        for (int p = 0; p < 16; ++p) t += red[n * 16 + p];
        t += bias[n];
        out[row * 16 + n] = gelu_exact(t);
    }
}

// ---------------------------------------------------------------------------
// final up + residuals: v = x2 + ffn + 0.5*(adp1 @ w_up + b_up)   (f32)
// ---------------------------------------------------------------------------
__global__ __launch_bounds__(256)
void final_up_kernel(const float* __restrict__ adp1, const float* __restrict__ w_up,
                     const float* __restrict__ b_up, const float* __restrict__ x2,
                     const float* __restrict__ ffn, float* __restrict__ out,
                     float* __restrict__ feat)
{
    __shared__ float a[16];
    long long row = blockIdx.x;
    int tid = threadIdx.x;
    if (tid < 16) a[tid] = adp1[row * 16 + tid];
    __syncthreads();
    int b = (int)(row / SEQ);
    int s = (int)(row % SEQ);
    #pragma unroll
    for (int i = 0; i < 3; ++i) {
        int c = tid + i * 256;
        float acc = b_up[c];
        #pragma unroll
        for (int k = 0; k < 16; ++k) acc += a[k] * w_up[k * CDIM + c];
        float v = x2[row * CDIM + c] + ffn[row * CDIM + c] + 0.5f * acc;
        out[row * CDIM + c] = v;
        if (s > 0)
            feat[((long long)b * GTOK + (s - 1)) * CDIM + c] = v;
    }
}

// ---------------------------------------------------------------------------
// Deterministic segment max+mean, compacted: per-thread strip scan (32 idx),
// stable block exclusive-scan -> sorted match list -> coalesced row loads.
// Same accumulation order as the old serial scan (ascending row index).
// Fallback to serial scan if total > SEGCAP (statistically impossible).
// ---------------------------------------------------------------------------
__global__ __launch_bounds__(256)
void seg_kernel(const float* __restrict__ feat, const int* __restrict__ idx,
                float* __restrict__ y)
{
    __shared__ int sidx[NFEAT];     // 32 KB
    __shared__ int list[SEGCAP];    // 8 KB
    __shared__ int offs[256];
    int seg = blockIdx.x;
    int tid = threadIdx.x;
    for (int j = tid; j < NFEAT; j += 256) sidx[j] = idx[j];
    __syncthreads();

    // per-thread strip count
    int base = tid * 32;
    int cnt = 0;
    #pragma unroll
    for (int i = 0; i < 32; ++i) cnt += (sidx[base + i] == seg) ? 1 : 0;
    offs[tid] = cnt;
    __syncthreads();
    // inclusive Hillis-Steele scan
    for (int st = 1; st < 256; st <<= 1) {
        int v = (tid >= st) ? offs[tid - st] : 0;
        __syncthreads();
        offs[tid] += v;
        __syncthreads();
    }
    int total = offs[255];
    int pos = offs[tid] - cnt;      // exclusive prefix
    __syncthreads();

    float mx0 = -FLT_MAX, mx1 = -FLT_MAX, mx2 = -FLT_MAX;
    float s0 = 0.f, s1 = 0.f, s2 = 0.f;

    if (total <= SEGCAP) {
        #pragma unroll
        for (int i = 0; i < 32; ++i) {
            int j = base + i;
            if (sidx[j] == seg) list[pos++] = j;
        }
        __syncthreads();
        for (int i = 0; i < total; ++i) {
            const float* fr = feat + (long long)list[i] * CDIM;
            float v0 = fr[tid], v1 = fr[tid + 256], v2 = fr[tid + 512];
            s0 += v0; s1 += v1; s2 += v2;
            mx0 = fmaxf(mx0, v0); mx1 = fmaxf(mx1, v1); mx2 = fmaxf(mx2, v2);
        }
    } else {
        // fallback: old serial scan (deterministic, never expected)
        for (int j = 0; j < NFEAT; ++j) {
            if (sidx[j] == seg) {
                const float* fr = feat + (long long)j * CDIM;
                float v0 = fr[tid], v1 = fr[tid + 256], v2 = fr[tid + 512];
                s0 += v0; s1 += v1; s2 += v2;
                mx0 = fmaxf(mx0, v0); mx1 = fmaxf(mx1, v1); mx2 = fmaxf(mx2, v2);
            }
        }
    }

    if (total == 0) { mx0 = mx1 = mx2 = 0.f; }
    float inv = 1.f / (float)(total > 0 ? total : 1);
    float* yr = y + (long long)seg * CDIM;
    yr[tid]       = mx0 + s0 * inv;
    yr[tid + 256] = mx1 + s1 * inv;
    yr[tid + 512] = mx2 + s2 * inv;
}

// ---------------------------------------------------------------------------
// BatchNorm over rows (two-pass) + exact GELU -> bf16
// ---------------------------------------------------------------------------
__global__ __launch_bounds__(128)
void bn_gelu_kernel(const float* __restrict__ y, const float* __restrict__ g,
                    const float* __restrict__ b, long long goff,
                    bf16* __restrict__ out, int R)
{
    __shared__ float red[128];
    int c = blockIdx.x;
    int tid = threadIdx.x;
    float s = 0.f;
    for (int r = tid; r < R; r += 128) s += y[(long long)r * CDIM + c];
    float mean = block_reduce_sum(s, red) / (float)R;
    float ss = 0.f;
    for (int r = tid; r < R; r += 128) {
        float d = y[(long long)r * CDIM + c] - mean;
        ss += d * d;
    }
    float var = fmaxf(block_reduce_sum(ss, red) / (float)R, 0.f);
    float rstd = rsqrtf(var + 1e-5f);
    float gc = g[goff + c], bc = b[goff + c];
    for (int r = tid; r < R; r += 128) {
        float v = (y[(long long)r * CDIM + c] - mean) * rstd * gc + bc;
        out[(long long)r * CDIM + c] = f2b(gelu_exact(v));
    }
}

// ---------------------------------------------------------------------------
// Final fusion: cosine sims over 6 views, weighted sum, write f32 out rows
// ---------------------------------------------------------------------------
__global__ __launch_bounds__(256)
void fuse_final_kernel(const float* __restrict__ feat, const bf16* __restrict__ bn3d,
                       const bf16* __restrict__ bn1d, const int* __restrict__ cluster,
                       const int* __restrict__ fgi, float* __restrict__ out)
{
    __shared__ float red[256];
    __shared__ float simsh[NVIEW];
    int j = blockIdx.x;
    int tid = threadIdx.x;
    int b = j >> 10, g = j & 1023;
    const bf16* x3 = bn3d + (long long)cluster[j] * CDIM;
    float s = 0.f;
    for (int c = tid; c < CDIM; c += 256) { float v = b2f(x3[c]); s += v * v; }
    float nx3 = fmaxf(sqrtf(block_reduce_sum(s, red)), 1e-8f);

    for (int i = 0; i < NVIEW; ++i) {
        const bf16* p = bn1d + ((long long)i * NGRID + fgi[i * NFEAT + j]) * CDIM;
        float d = 0.f, nn = 0.f;
        for (int c = tid; c < CDIM; c += 256) {
            float pv = b2f(p[c]);
            d += pv * b2f(x3[c]); nn += pv * pv;
        }
        float D = block_reduce_sum(d, red);
        float Np = sqrtf(block_reduce_sum(nn, red));
        if (tid == 0) {
            float cosv = D / (fmaxf(Np, 1e-8f) * nx3);
            simsh[i] = (cosv + 1.f) * 0.5f;
        }
        __syncthreads();
    }
    float ssum = 0.f;
    #pragma unroll
    for (int i = 0; i < NVIEW; ++i) ssum += simsh[i];
    float invs = 1.f / fmaxf(ssum, 1e-20f);
    long long orow = ((long long)b * SEQ + 1 + g) * CDIM;
    for (int c = tid; c < CDIM; c += 256) {
        float acc = 0.f;
        #pragma unroll
        for (int i = 0; i < NVIEW; ++i) {
            const bf16* p = bn1d + ((long long)i * NGRID + fgi[i * NFEAT + j]) * CDIM;
            acc += simsh[i] * invs * b2f(p[c]);
        }
        out[orow + c] = feat[(long long)j * CDIM + c] + 0.3f * acc;
    }
}

// ---------------------------------------------------------------------------
// Host side
// ---------------------------------------------------------------------------
extern "C" void kernel_launch(void* const* d_in, const int* in_sizes, int n_in,
                              void* d_out, int out_size, void* d_ws, size_t ws_size,
                              hipStream_t stream)
{
    const float* x      = (const float*)d_in[0];
    const int*  cluster = (const int*)d_in[2];
    const int*  fgi     = (const int*)d_in[3];
    const float* ln1_g = (const float*)d_in[6];
    const float* ln1_b = (const float*)d_in[7];
    const float* w_qkv = (const float*)d_in[8];
    const float* b_qkv = (const float*)d_in[9];
    const float* w_o   = (const float*)d_in[10];
    const float* b_o   = (const float*)d_in[11];
    const float* ln2_g = (const float*)d_in[12];
    const float* ln2_b = (const float*)d_in[13];
    const float* w_fc  = (const float*)d_in[14];
    const float* b_fc  = (const float*)d_in[15];
    const float* w_proj= (const float*)d_in[16];
    const float* b_proj= (const float*)d_in[17];
    const float* w_down= (const float*)d_in[18];
    const float* b_down= (const float*)d_in[19];
    const float* w_up  = (const float*)d_in[20];
    const float* b_up  = (const float*)d_in[21];
    const float* bn3d_g= (const float*)d_in[22];
    const float* bn3d_b= (const float*)d_in[23];
    const float* n3_g  = (const float*)d_in[24];
    const float* n3_b  = (const float*)d_in[25];
    const float* vw_qkv= (const float*)d_in[26];
    const float* vb_qkv= (const float*)d_in[27];
    const float* vw_o  = (const float*)d_in[28];
    const float* vb_o  = (const float*)d_in[29];
    const float* bn1d_g= (const float*)d_in[30];
    const float* bn1d_b= (const float*)d_in[31];
    (void)in_sizes; (void)n_in; (void)out_size; (void)ws_size;

    float* out = (float*)d_out;

    // workspace layout (bytes), total ~185.1 MB
    char* w = (char*)d_ws;
    bf16*  QKV  = (bf16*)w;  w += (long long)NROWS * 3 * CDIM * 2;    // 37.8 MB
    bf16*  H    = (bf16*)w;  w += (long long)NROWS * CDIM * 2;        // 12.6 MB
    float* X2   = (float*)w; w += (long long)NROWS * CDIM * 4;        // 25.2 MB
    bf16*  AO   = (bf16*)w;  w += (long long)NROWS * CDIM * 2;        // 12.6 MB
    float* FFN  = (float*)w; w += (long long)NROWS * CDIM * 4;        // 25.2 MB
    float* T1   = (float*)w; w += (long long)BATCH * SEQ * SEQ * 4;   // 33.6 MB
    float* ADP  = (float*)w; w += (long long)NROWS * 16 * 4;          // 0.5 MB
    float* FEAT = (float*)w; w += (long long)NFEAT * CDIM * 4;        // 25.2 MB
    float* Y512 = (float*)w; w += (long long)NCLUST * CDIM * 4;       // 1.6 MB
    bf16*  BN3D = (bf16*)w;  w += (long long)NCLUST * CDIM * 2;       // 0.8 MB
    float* YG   = (float*)w; w += (long long)NGRID * CDIM * 4;        // 4.8 MB
    bf16*  BN1D = (bf16*)w;  w += (long long)NVIEW * NGRID * CDIM * 2;// 14.5 MB

    dim3 blk(256);

    // ---- stage A: transformer block ----
    ln_kernel<<<NROWS, blk, 0, stream>>>(x, ln1_g, ln1_b, 0LL, H);

    gemm_k<0,0,1,0,0><<<dim3(36, 129, 1), blk, 0, stream>>>(
        H, w_qkv, b_qkv, nullptr, QKV,
        NROWS, 3*CDIM, CDIM, CDIM, 3*CDIM, 3*CDIM, 0, 1.f, 0, 0LL, 0LL, 0, 0, 0);

    // ---- main attention via per-head MFMA GEMMs ----
    for (int h = 0; h < NHEAD; ++h) {
        gemm_k<1,0,0,1,0><<<dim3(17, 17, BATCH), blk, 0, stream>>>(
            QKV + h * DHEAD, QKV + CDIM + h * DHEAD, nullptr, nullptr, T1,
            SEQ, SEQ, DHEAD, 3*CDIM, 3*CDIM, SEQ, 0, 0.125f, 0, 0LL, 0LL,
            (long long)SEQ * 3*CDIM, (long long)SEQ * 3*CDIM, (long long)SEQ * SEQ);

        softmax_aw_kernel<<<NROWS, blk, 0, stream>>>(T1, out, h == 0 ? 1 : 0);

        gemm_k<0,1,0,0,0><<<dim3(1, 17, BATCH), blk, 0, stream>>>(
            T1, QKV + 2*CDIM + h * DHEAD, nullptr, nullptr, AO + h * DHEAD,
            SEQ, DHEAD, SEQ, SEQ, 3*CDIM, CDIM, 0, 1.f, 0, 0LL, 0LL,
            (long long)SEQ * SEQ, (long long)SEQ * 3*CDIM, (long long)SEQ * CDIM);
    }

    // x2 = AO @ w_o + b_o + x   -> f32
    gemm_k<0,0,1,1,1><<<dim3(12, 129, 1), blk, 0, stream>>>(
        AO, w_o, b_o, x, X2,
        NROWS, CDIM, CDIM, CDIM, CDIM, CDIM, CDIM, 1.f, 0, 0LL, 0LL, 0, 0, 0);

    ln_kernel<<<NROWS, blk, 0, stream>>>(X2, ln2_g, ln2_b, 0LL, H);

    // FC + proj in 2 row-chunks of 4100; bf16 MID shares T1
    {
        bf16* MID = (bf16*)T1;
        for (int cidx = 0; cidx < 2; ++cidx) {
            long long r0 = 4100LL * cidx;
            int m = 4100;
            gemm_k<0,0,1,0,0><<<dim3(48, 65, 1), blk, 0, stream>>>(
                H + r0 * CDIM, w_fc, b_fc, nullptr, MID,
                m, 4*CDIM, CDIM, CDIM, 4*CDIM, 4*CDIM, 0, 1.f, 1, 0LL, 0LL, 0, 0, 0);
            gemm_k<0,0,1,1,0><<<dim3(12, 65, 1), blk, 0, stream>>>(
                MID, w_proj, b_proj, nullptr, FFN + r0 * CDIM,
                m, CDIM, 4*CDIM, 4*CDIM, CDIM, CDIM, 0, 1.f, 0, 0LL, 0LL, 0, 0, 0);
        }
    }

    adp_down_kernel<<<NROWS, blk, 0, stream>>>(FFN, w_down, b_down, ADP);
    final_up_kernel<<<NROWS, blk, 0, stream>>>(ADP, w_up, b_up, X2, FFN, out, FEAT);

    // ---- stage B: cluster pooling + BN-GELU ----
    seg_kernel<<<NCLUST, blk, 0, stream>>>(FEAT, cluster, Y512);
    bn_gelu_kernel<<<CDIM, dim3(128), 0, stream>>>(Y512, bn3d_g, bn3d_b, 0LL, BN3D, NCLUST);

    // ---- stage C: 6 views ----
    const float inv_sqrt_c = 0.03608439182435161f; // 1/sqrt(768)
    for (int i = 0; i < NVIEW; ++i) {
        ln_kernel<<<NFEAT, blk, 0, stream>>>(FEAT, n3_g, n3_b, (long long)i * CDIM, H);

        gemm_k<0,0,1,0,0><<<dim3(36, 128, 1), blk, 0, stream>>>(
            H, vw_qkv, vb_qkv, nullptr, QKV,
            NFEAT, 3*CDIM, CDIM, CDIM, 3*CDIM, 3*CDIM, 0, 1.f, 0,
            (long long)i * CDIM * 3*CDIM, (long long)i * 3*CDIM, 0, 0, 0);

        gemm_k<1,0,0,1,0><<<dim3(16, 16, BATCH), blk, 0, stream>>>(
            QKV, QKV + CDIM, nullptr, nullptr, T1,
            GTOK, GTOK, CDIM, 3*CDIM, 3*CDIM, GTOK, 0, inv_sqrt_c, 0, 0LL, 0LL,
            (long long)GTOK * 3*CDIM, (long long)GTOK * 3*CDIM, (long long)GTOK * GTOK);

        softmax_rows<<<BATCH * GTOK, blk, 0, stream>>>(T1);

        gemm_k<0,1,0,0,0><<<dim3(12, 16, BATCH), blk, 0, stream>>>(
            T1, QKV + 2*CDIM, nullptr, nullptr, AO,
            GTOK, CDIM, GTOK, GTOK, 3*CDIM, CDIM, 0, 1.f, 0, 0LL, 0LL,
            (long long)GTOK * GTOK, (long long)GTOK * 3*CDIM, (long long)GTOK * CDIM);

        gemm_k<0,0,1,1,1><<<dim3(12, 128, 1), blk, 0, stream>>>(
            AO, vw_o, vb_o, FEAT, X2,
            NFEAT, CDIM, CDIM, CDIM, CDIM, CDIM, CDIM, 1.f, 0,
            (long long)i * CDIM * CDIM, (long long)i * CDIM, 0, 0, 0);

        seg_kernel<<<NGRID, blk, 0, stream>>>(X2, fgi + i * NFEAT, YG);
        bn_gelu_kernel<<<CDIM, dim3(128), 0, stream>>>(
            YG, bn1d_g, bn1d_b, (long long)i * CDIM,
            BN1D + (long long)i * NGRID * CDIM, NGRID);
    }

    // ---- final fusion ----
    fuse_final_kernel<<<NFEAT, blk, 0, stream>>>(FEAT, BN3D, BN1D, cluster, fgi, out);
}

// Round 12
// 5635.785 us; speedup vs baseline: 3.9791x; 1.1851x over previous
//
#include <hip/hip_runtime.h>
#include <math.h>
#include <float.h>

#define BATCH   8
#define SEQ     1025
#define GTOK    1024
#define CDIM    768
#define NHEAD   12
#define DHEAD   64
#define NVIEW   6
#define NCLUST  512
#define NGRID   1568
#define NROWS   8200
#define NFEAT   8192
#define SEGCAP  2048

typedef unsigned short bf16;
typedef __attribute__((ext_vector_type(8))) short bf16x8;
typedef __attribute__((ext_vector_type(4))) float f32x4;

__device__ __forceinline__ float b2f(bf16 u) {
    union { unsigned int i; float f; } v; v.i = ((unsigned int)u) << 16; return v.f;
}
__device__ __forceinline__ bf16 f2b(float f) {
    union { float f; unsigned int i; } v; v.f = f;
    unsigned int x = v.i;
    return (bf16)((x + 0x7fffu + ((x >> 16) & 1u)) >> 16);
}

__device__ __forceinline__ float block_reduce_sum(float v, float* red) {
    int tid = threadIdx.x;
    red[tid] = v; __syncthreads();
    for (int s = blockDim.x >> 1; s > 0; s >>= 1) {
        if (tid < s) red[tid] += red[tid + s];
        __syncthreads();
    }
    float r = red[0]; __syncthreads();
    return r;
}

__device__ __forceinline__ float gelu_exact(float v) {
    return 0.5f * v * (1.f + erff(v * 0.70710678118654752f));
}
__device__ __forceinline__ float quick_gelu(float v) {
    return v / (1.f + expf(-1.702f * v));
}

// ---------------------------------------------------------------------------
// LayerNorm: one block per row (f32 input, f32 gamma/beta, bf16 out)
// ---------------------------------------------------------------------------
__global__ __launch_bounds__(256)
void ln_kernel(const float* __restrict__ x, const float* __restrict__ g,
               const float* __restrict__ b, long long goff, bf16* __restrict__ out)
{
    __shared__ float red[256];
    long long row = blockIdx.x;
    int tid = threadIdx.x;
    long long base = row * CDIM;
    float v0 = x[base + tid], v1 = x[base + tid + 256], v2 = x[base + tid + 512];
    float mean = block_reduce_sum(v0 + v1 + v2, red) * (1.f / CDIM);
    float d0 = v0 - mean, d1 = v1 - mean, d2 = v2 - mean;
    float var = block_reduce_sum(d0 * d0 + d1 * d1 + d2 * d2, red) * (1.f / CDIM);
    float rstd = rsqrtf(var + 1e-5f);
    bf16* orow = out + base;
    orow[tid]       = f2b(d0 * rstd * g[goff + tid]       + b[goff + tid]);
    orow[tid + 256] = f2b(d1 * rstd * g[goff + tid + 256] + b[goff + tid + 256]);
    orow[tid + 512] = f2b(d2 * rstd * g[goff + tid + 512] + b[goff + tid + 512]);
}

// ---------------------------------------------------------------------------
// gemm_k: 64x64-tile MFMA GEMM (proven; kept for narrow-N / odd-K cases)
// ---------------------------------------------------------------------------
#define LDSK 40

template<int TRANSB, int ATY, int BSRC, int OTY, int RES>
__global__ __launch_bounds__(256)
void gemm_k(const void* __restrict__ Av, const void* __restrict__ B,
            const void* __restrict__ bias, const float* __restrict__ Res,
            void* __restrict__ Cv,
            int M, int N, int K, int lda, int ldb, int ldc, int ldres,
            float alpha, int act, long long boff, long long biasoff,
            long long sA, long long sB, long long sC)
{
    __shared__ short As[64][LDSK];
    __shared__ short Bs[64][LDSK];
    int bz = blockIdx.z;
    int tid = threadIdx.x;
    int m0 = blockIdx.y * 64, n0 = blockIdx.x * 64;
    long long Aoff = (long long)bz * sA;
    long long Boff = boff + (long long)bz * sB;

    int lane = tid & 63;
    int w = tid >> 6;
    int wr = w >> 1, wc = w & 1;
    int fr = lane & 15;
    int kg = lane >> 4;

    f32x4 acc[2][2] = {};

    for (int k0 = 0; k0 < K; k0 += 32) {
        {
            int r = tid >> 2, kb = (tid & 3) * 8;
            int gm = m0 + r;
            short tmp[8] = {};
            if (gm < M) {
                long long base = Aoff + (long long)gm * lda + k0 + kb;
                if (k0 + kb + 8 <= K) {
                    if (ATY == 0) {
                        *reinterpret_cast<uint4*>(tmp) =
                            *reinterpret_cast<const uint4*>((const bf16*)Av + base);
                    } else {
                        float4 f0 = *reinterpret_cast<const float4*>((const float*)Av + base);
                        float4 f1 = *reinterpret_cast<const float4*>((const float*)Av + base + 4);
                        tmp[0]=(short)f2b(f0.x); tmp[1]=(short)f2b(f0.y);
                        tmp[2]=(short)f2b(f0.z); tmp[3]=(short)f2b(f0.w);
                        tmp[4]=(short)f2b(f1.x); tmp[5]=(short)f2b(f1.y);
                        tmp[6]=(short)f2b(f1.z); tmp[7]=(short)f2b(f1.w);
                    }
                } else {
                    #pragma unroll
                    for (int j = 0; j < 8; ++j) {
                        if (k0 + kb + j < K)
                            tmp[j] = ATY ? (short)f2b(((const float*)Av)[base + j])
                                         : (short)((const bf16*)Av)[base + j];
                    }
                }
            }
            *reinterpret_cast<uint4*>(&As[r][kb]) = *reinterpret_cast<uint4*>(tmp);
        }
        {
            int col = tid >> 2, kb = (tid & 3) * 8;
            int gn = n0 + col;
            short tmp[8] = {};
            if (gn < N) {
                if (TRANSB) {
                    long long base = Boff + (long long)gn * ldb + k0 + kb;
                    if (k0 + kb + 8 <= K) {
                        if (BSRC == 0) {
                            *reinterpret_cast<uint4*>(tmp) =
                                *reinterpret_cast<const uint4*>((const bf16*)B + base);
                        } else {
                            float4 f0 = *reinterpret_cast<const float4*>((const float*)B + base);
                            float4 f1 = *reinterpret_cast<const float4*>((const float*)B + base + 4);
                            tmp[0]=(short)f2b(f0.x); tmp[1]=(short)f2b(f0.y);
                            tmp[2]=(short)f2b(f0.z); tmp[3]=(short)f2b(f0.w);
                            tmp[4]=(short)f2b(f1.x); tmp[5]=(short)f2b(f1.y);
                            tmp[6]=(short)f2b(f1.z); tmp[7]=(short)f2b(f1.w);
                        }
                    } else {
                        #pragma unroll
                        for (int j = 0; j < 8; ++j) {
                            if (k0 + kb + j < K)
                                tmp[j] = BSRC ? (short)f2b(((const float*)B)[base + j])
                                              : (short)((const bf16*)B)[base + j];
                        }
                    }
                } else {
                    #pragma unroll
                    for (int j = 0; j < 8; ++j) {
                        int kk = k0 + kb + j;
                        if (kk < K) {
                            long long bi = Boff + (long long)kk * ldb + gn;
                            tmp[j] = BSRC ? (short)f2b(((const float*)B)[bi])
                                          : (short)((const bf16*)B)[bi];
                        }
                    }
                }
            }
            *reinterpret_cast<uint4*>(&Bs[col][kb]) = *reinterpret_cast<uint4*>(tmp);
        }
        __syncthreads();

        bf16x8 a0 = *reinterpret_cast<const bf16x8*>(&As[wr * 32 + fr][kg * 8]);
        bf16x8 a1 = *reinterpret_cast<const bf16x8*>(&As[wr * 32 + 16 + fr][kg * 8]);
        bf16x8 b0 = *reinterpret_cast<const bf16x8*>(&Bs[wc * 32 + fr][kg * 8]);
        bf16x8 b1 = *reinterpret_cast<const bf16x8*>(&Bs[wc * 32 + 16 + fr][kg * 8]);
        acc[0][0] = __builtin_amdgcn_mfma_f32_16x16x32_bf16(a0, b0, acc[0][0], 0, 0, 0);
        acc[0][1] = __builtin_amdgcn_mfma_f32_16x16x32_bf16(a0, b1, acc[0][1], 0, 0, 0);
        acc[1][0] = __builtin_amdgcn_mfma_f32_16x16x32_bf16(a1, b0, acc[1][0], 0, 0, 0);
        acc[1][1] = __builtin_amdgcn_mfma_f32_16x16x32_bf16(a1, b1, acc[1][1], 0, 0, 0);
        __syncthreads();
    }

    #pragma unroll
    for (int m = 0; m < 2; ++m) {
        #pragma unroll
        for (int n = 0; n < 2; ++n) {
            #pragma unroll
            for (int i = 0; i < 4; ++i) {
                int gm = m0 + wr * 32 + m * 16 + kg * 4 + i;
                int gn = n0 + wc * 32 + n * 16 + fr;
                if (gm >= M || gn >= N) continue;
                float v = acc[m][n][i] * alpha;
                if (bias) v += BSRC ? ((const float*)bias)[biasoff + gn]
                                    : b2f(((const bf16*)bias)[biasoff + gn]);
                if (act == 1) v = quick_gelu(v);
                if (RES) v += Res[(long long)gm * ldres + gn];
                long long ci = sC * bz + (long long)gm * ldc + gn;
                if (OTY) ((float*)Cv)[ci] = v;
                else     ((bf16*)Cv)[ci] = f2b(v);
            }
        }
    }
}

// ---------------------------------------------------------------------------
// gemm2: 128x128-tile MFMA GEMM, BK=32, 4 waves in 2x2, 4x4 frags/wave
// (16 MFMA + 8 ds_read_b128 per wave per K-step). Requires K % 32 == 0.
// M/N edges guarded. Same parameterization as gemm_k.
// ---------------------------------------------------------------------------
template<int TRANSB, int ATY, int BSRC, int OTY, int RES>
__global__ __launch_bounds__(256)
void gemm2(const void* __restrict__ Av, const void* __restrict__ B,
           const void* __restrict__ bias, const float* __restrict__ Res,
           void* __restrict__ Cv,
           int M, int N, int K, int lda, int ldb, int ldc, int ldres,
           float alpha, int act, long long boff, long long biasoff,
           long long sA, long long sB, long long sC)
{
    __shared__ short As[128][LDSK];
    __shared__ short Bs[128][LDSK];
    int bz = blockIdx.z;
    int tid = threadIdx.x;
    int m0 = blockIdx.y * 128, n0 = blockIdx.x * 128;
    long long Aoff = (long long)bz * sA;
    long long Boff = boff + (long long)bz * sB;

    int lane = tid & 63;
    int w = tid >> 6;
    int wr = w >> 1, wc = w & 1;
    int fr = lane & 15;
    int kg = lane >> 4;

    f32x4 acc[4][4] = {};

    for (int k0 = 0; k0 < K; k0 += 32) {
        // ---- stage A: thread t loads 16 contiguous k of row t>>1
        {
            int r = tid >> 1, kb = (tid & 1) * 16;
            int gm = m0 + r;
            short tmp[16] = {};
            if (gm < M) {
                long long base = Aoff + (long long)gm * lda + k0 + kb;
                if (ATY == 0) {
                    *reinterpret_cast<uint4*>(tmp) =
                        *reinterpret_cast<const uint4*>((const bf16*)Av + base);
                    *reinterpret_cast<uint4*>(tmp + 8) =
                        *reinterpret_cast<const uint4*>((const bf16*)Av + base + 8);
                } else {
                    #pragma unroll
                    for (int q = 0; q < 4; ++q) {
                        float4 f = *reinterpret_cast<const float4*>((const float*)Av + base + q * 4);
                        tmp[q*4+0]=(short)f2b(f.x); tmp[q*4+1]=(short)f2b(f.y);
                        tmp[q*4+2]=(short)f2b(f.z); tmp[q*4+3]=(short)f2b(f.w);
                    }
                }
            }
            *reinterpret_cast<uint4*>(&As[r][kb])     = *reinterpret_cast<uint4*>(tmp);
            *reinterpret_cast<uint4*>(&As[r][kb + 8]) = *reinterpret_cast<uint4*>(tmp + 8);
        }
        // ---- stage B: Bs[col][k]
        {
            int col = tid >> 1, kb = (tid & 1) * 16;
            int gn = n0 + col;
            short tmp[16] = {};
            if (gn < N) {
                if (TRANSB) {
                    long long base = Boff + (long long)gn * ldb + k0 + kb;
                    if (BSRC == 0) {
                        *reinterpret_cast<uint4*>(tmp) =
                            *reinterpret_cast<const uint4*>((const bf16*)B + base);
                        *reinterpret_cast<uint4*>(tmp + 8) =
                            *reinterpret_cast<const uint4*>((const bf16*)B + base + 8);
                    } else {
                        #pragma unroll
                        for (int q = 0; q < 4; ++q) {
                            float4 f = *reinterpret_cast<const float4*>((const float*)B + base + q * 4);
                            tmp[q*4+0]=(short)f2b(f.x); tmp[q*4+1]=(short)f2b(f.y);
                            tmp[q*4+2]=(short)f2b(f.z); tmp[q*4+3]=(short)f2b(f.w);
                        }
                    }
                } else {
                    #pragma unroll
                    for (int j = 0; j < 16; ++j) {
                        long long bi = Boff + (long long)(k0 + kb + j) * ldb + gn;
                        tmp[j] = BSRC ? (short)f2b(((const float*)B)[bi])
                                      : (short)((const bf16*)B)[bi];
                    }
                }
            }
            *reinterpret_cast<uint4*>(&Bs[col][kb])     = *reinterpret_cast<uint4*>(tmp);
            *reinterpret_cast<uint4*>(&Bs[col][kb + 8]) = *reinterpret_cast<uint4*>(tmp + 8);
        }
        __syncthreads();

        bf16x8 a[4], bq[4];
        #pragma unroll
        for (int m = 0; m < 4; ++m)
            a[m] = *reinterpret_cast<const bf16x8*>(&As[wr * 64 + m * 16 + fr][kg * 8]);
        #pragma unroll
        for (int n = 0; n < 4; ++n)
            bq[n] = *reinterpret_cast<const bf16x8*>(&Bs[wc * 64 + n * 16 + fr][kg * 8]);
        #pragma unroll
        for (int m = 0; m < 4; ++m)
            #pragma unroll
            for (int n = 0; n < 4; ++n)
                acc[m][n] = __builtin_amdgcn_mfma_f32_16x16x32_bf16(a[m], bq[n], acc[m][n], 0, 0, 0);
        __syncthreads();
    }

    #pragma unroll
    for (int m = 0; m < 4; ++m) {
        #pragma unroll
        for (int n = 0; n < 4; ++n) {
            #pragma unroll
            for (int i = 0; i < 4; ++i) {
                int gm = m0 + wr * 64 + m * 16 + kg * 4 + i;
                int gn = n0 + wc * 64 + n * 16 + fr;
                if (gm >= M || gn >= N) continue;
                float v = acc[m][n][i] * alpha;
                if (bias) v += BSRC ? ((const float*)bias)[biasoff + gn]
                                    : b2f(((const bf16*)bias)[biasoff + gn]);
                if (act == 1) v = quick_gelu(v);
                if (RES) v += Res[(long long)gm * ldres + gn];
                long long ci = sC * bz + (long long)gm * ldc + gn;
                if (OTY) ((float*)Cv)[ci] = v;
                else     ((bf16*)Cv)[ci] = f2b(v);
            }
        }
    }
}

// ---------------------------------------------------------------------------
// Fused softmax + attn_weight accumulate for main attention.
// ---------------------------------------------------------------------------
__global__ __launch_bounds__(256)
void softmax_aw_kernel(float* __restrict__ T1, float* __restrict__ out, int first)
{
    __shared__ float red[256];
    long long r = blockIdx.x;
    float* sr = T1 + r * SEQ;
    float* aw = out + (long long)NROWS * CDIM + r * SEQ;
    int tid = threadIdx.x;

    float lmax = -FLT_MAX;
    for (int k = tid; k < SEQ; k += 256) lmax = fmaxf(lmax, sr[k]);
    red[tid] = lmax; __syncthreads();
    for (int st = 128; st > 0; st >>= 1) {
        if (tid < st) red[tid] = fmaxf(red[tid], red[tid + st]);
        __syncthreads();
    }
    float m = red[0]; __syncthreads();

    float ls = 0.f;
    for (int k = tid; k < SEQ; k += 256) {
        float p = expf(sr[k] - m);
        sr[k] = p; ls += p;
    }
    float Z = block_reduce_sum(ls, red);
    float inv = 1.f / fmaxf(Z, 1e-30f);
    const float hscale = 1.f / (float)NHEAD;
    for (int k = tid; k < SEQ; k += 256) {
        float p = sr[k] * inv;
        sr[k] = p;
        aw[k] = (first ? 0.f : aw[k]) + p * hscale;
    }
}

// ---------------------------------------------------------------------------
// Row softmax on f32 rows of width 1024, in place (view attention)
// ---------------------------------------------------------------------------
__global__ __launch_bounds__(256)
void softmax_rows(float* __restrict__ s)
{
    __shared__ float red[256];
    long long row = blockIdx.x;
    float* sr = s + row * GTOK;
    int tid = threadIdx.x;
    float v[4];
    float lmax = -FLT_MAX;
    #pragma unroll
    for (int i = 0; i < 4; ++i) { v[i] = sr[tid + i * 256]; lmax = fmaxf(lmax, v[i]); }
    red[tid] = lmax; __syncthreads();
    for (int st = 128; st > 0; st >>= 1) {
        if (tid < st) red[tid] = fmaxf(red[tid], red[tid + st]);
        __syncthreads();
    }
    float m = red[0]; __syncthreads();
    float ls = 0.f;
    #pragma unroll
    for (int i = 0; i < 4; ++i) { v[i] = expf(v[i] - m); ls += v[i]; }
    float Z = block_reduce_sum(ls, red);
    float inv = 1.f / fmaxf(Z, 1e-30f);
    #pragma unroll
    for (int i = 0; i < 4; ++i) sr[tid + i * 256] = v[i] * inv;
}

// ---------------------------------------------------------------------------
// adapter down: adp1 = gelu(ffn @ w_down + b_down) -> f32 (NROWS,16)
// ---------------------------------------------------------------------------
__global__ __launch_bounds__(256)
void adp_down_kernel(const float* __restrict__ ffn, const float* __restrict__ w,
                     const float* __restrict__ bias, float* __restrict__ out)
{
    __shared__ float rowsh[CDIM];
    __shared__ float red[256];
    long long row = blockIdx.x;
    int tid = threadIdx.x;
    for (int c = tid; c < CDIM; c += 256) rowsh[c] = ffn[row * CDIM + c];
    __syncthreads();
    int n = tid >> 4;
    int part = tid & 15;
    float s = 0.f;
    for (int i = part; i < CDIM; i += 16) s += rowsh[i] * w[i * 16 + n];
    red[tid] = s; __syncthreads();
    if (part == 0) {
        float t = 0.f;
        #pragma unroll
        for (int p = 0; p < 16; ++p) t += red[n * 16 + p];
        t += bias[n];
        out[row * 16 + n] = gelu_exact(t);
    }
}

// ---------------------------------------------------------------------------
// final up + residuals: v = x2 + ffn + 0.5*(adp1 @ w_up + b_up)   (f32)
// ---------------------------------------------------------------------------
__global__ __launch_bounds__(256)
void final_up_kernel(const float* __restrict__ adp1, const float* __restrict__ w_up,
                     const float* __restrict__ b_up, const float* __restrict__ x2,
                     const float* __restrict__ ffn, float* __restrict__ out,
                     float* __restrict__ feat)
{
    __shared__ float a[16];
    long long row = blockIdx.x;
    int tid = threadIdx.x;
    if (tid < 16) a[tid] = adp1[row * 16 + tid];
    __syncthreads();
    int b = (int)(row / SEQ);
    int s = (int)(row % SEQ);
    #pragma unroll
    for (int i = 0; i < 3; ++i) {
        int c = tid + i * 256;
        float acc = b_up[c];
        #pragma unroll
        for (int k = 0; k < 16; ++k) acc += a[k] * w_up[k * CDIM + c];
        float v = x2[row * CDIM + c] + ffn[row * CDIM + c] + 0.5f * acc;
        out[row * CDIM + c] = v;
        if (s > 0)
            feat[((long long)b * GTOK + (s - 1)) * CDIM + c] = v;
    }
}

// ---------------------------------------------------------------------------
// Deterministic segment max+mean, compacted (round 11, proven)
// ---------------------------------------------------------------------------
__global__ __launch_bounds__(256)
void seg_kernel(const float* __restrict__ feat, const int* __restrict__ idx,
                float* __restrict__ y)
{
    __shared__ int sidx[NFEAT];
    __shared__ int list[SEGCAP];
    __shared__ int offs[256];
    int seg = blockIdx.x;
    int tid = threadIdx.x;
    for (int j = tid; j < NFEAT; j += 256) sidx[j] = idx[j];
    __syncthreads();

    int base = tid * 32;
    int cnt = 0;
    #pragma unroll
    for (int i = 0; i < 32; ++i) cnt += (sidx[base + i] == seg) ? 1 : 0;
    offs[tid] = cnt;
    __syncthreads();
    for (int st = 1; st < 256; st <<= 1) {
        int v = (tid >= st) ? offs[tid - st] : 0;
        __syncthreads();
        offs[tid] += v;
        __syncthreads();
    }
    int total = offs[255];
    int pos = offs[tid] - cnt;
    __syncthreads();

    float mx0 = -FLT_MAX, mx1 = -FLT_MAX, mx2 = -FLT_MAX;
    float s0 = 0.f, s1 = 0.f, s2 = 0.f;

    if (total <= SEGCAP) {
        #pragma unroll
        for (int i = 0; i < 32; ++i) {
            int j = base + i;
            if (sidx[j] == seg) list[pos++] = j;
        }
        __syncthreads();
        for (int i = 0; i < total; ++i) {
            const float* fr = feat + (long long)list[i] * CDIM;
            float v0 = fr[tid], v1 = fr[tid + 256], v2 = fr[tid + 512];
            s0 += v0; s1 += v1; s2 += v2;
            mx0 = fmaxf(mx0, v0); mx1 = fmaxf(mx1, v1); mx2 = fmaxf(mx2, v2);
        }
    } else {
        for (int j = 0; j < NFEAT; ++j) {
            if (sidx[j] == seg) {
                const float* fr = feat + (long long)j * CDIM;
                float v0 = fr[tid], v1 = fr[tid + 256], v2 = fr[tid + 512];
                s0 += v0; s1 += v1; s2 += v2;
                mx0 = fmaxf(mx0, v0); mx1 = fmaxf(mx1, v1); mx2 = fmaxf(mx2, v2);
            }
        }
    }

    if (total == 0) { mx0 = mx1 = mx2 = 0.f; }
    float inv = 1.f / (float)(total > 0 ? total : 1);
    float* yr = y + (long long)seg * CDIM;
    yr[tid]       = mx0 + s0 * inv;
    yr[tid + 256] = mx1 + s1 * inv;
    yr[tid + 512] = mx2 + s2 * inv;
}

// ---------------------------------------------------------------------------
// BatchNorm over rows (two-pass) + exact GELU -> bf16
// ---------------------------------------------------------------------------
__global__ __launch_bounds__(128)
void bn_gelu_kernel(const float* __restrict__ y, const float* __restrict__ g,
                    const float* __restrict__ b, long long goff,
                    bf16* __restrict__ out, int R)
{
    __shared__ float red[128];
    int c = blockIdx.x;
    int tid = threadIdx.x;
    float s = 0.f;
    for (int r = tid; r < R; r += 128) s += y[(long long)r * CDIM + c];
    float mean = block_reduce_sum(s, red) / (float)R;
    float ss = 0.f;
    for (int r = tid; r < R; r += 128) {
        float d = y[(long long)r * CDIM + c] - mean;
        ss += d * d;
    }
    float var = fmaxf(block_reduce_sum(ss, red) / (float)R, 0.f);
    float rstd = rsqrtf(var + 1e-5f);
    float gc = g[goff + c], bc = b[goff + c];
    for (int r = tid; r < R; r += 128) {
        float v = (y[(long long)r * CDIM + c] - mean) * rstd * gc + bc;
        out[(long long)r * CDIM + c] = f2b(gelu_exact(v));
    }
}

// ---------------------------------------------------------------------------
// Final fusion: cosine sims over 6 views, weighted sum, write f32 out rows
// ---------------------------------------------------------------------------
__global__ __launch_bounds__(256)
void fuse_final_kernel(const float* __restrict__ feat, const bf16* __restrict__ bn3d,
                       const bf16* __restrict__ bn1d, const int* __restrict__ cluster,
                       const int* __restrict__ fgi, float* __restrict__ out)
{
    __shared__ float red[256];
    __shared__ float simsh[NVIEW];
    int j = blockIdx.x;
    int tid = threadIdx.x;
    int b = j >> 10, g = j & 1023;
    const bf16* x3 = bn3d + (long long)cluster[j] * CDIM;
    float s = 0.f;
    for (int c = tid; c < CDIM; c += 256) { float v = b2f(x3[c]); s += v * v; }
    float nx3 = fmaxf(sqrtf(block_reduce_sum(s, red)), 1e-8f);

    for (int i = 0; i < NVIEW; ++i) {
        const bf16* p = bn1d + ((long long)i * NGRID + fgi[i * NFEAT + j]) * CDIM;
        float d = 0.f, nn = 0.f;
        for (int c = tid; c < CDIM; c += 256) {
            float pv = b2f(p[c]);
            d += pv * b2f(x3[c]); nn += pv * pv;
        }
        float D = block_reduce_sum(d, red);
        float Np = sqrtf(block_reduce_sum(nn, red));
        if (tid == 0) {
            float cosv = D / (fmaxf(Np, 1e-8f) * nx3);
            simsh[i] = (cosv + 1.f) * 0.5f;
        }
        __syncthreads();
    }
    float ssum = 0.f;
    #pragma unroll
    for (int i = 0; i < NVIEW; ++i) ssum += simsh[i];
    float invs = 1.f / fmaxf(ssum, 1e-20f);
    long long orow = ((long long)b * SEQ + 1 + g) * CDIM;
    for (int c = tid; c < CDIM; c += 256) {
        float acc = 0.f;
        #pragma unroll
        for (int i = 0; i < NVIEW; ++i) {
            const bf16* p = bn1d + ((long long)i * NGRID + fgi[i * NFEAT + j]) * CDIM;
            acc += simsh[i] * invs * b2f(p[c]);
        }
        out[orow + c] = feat[(long long)j * CDIM + c] + 0.3f * acc;
    }
}

// ---------------------------------------------------------------------------
// Host side
// ---------------------------------------------------------------------------
extern "C" void kernel_launch(void* const* d_in, const int* in_sizes, int n_in,
                              void* d_out, int out_size, void* d_ws, size_t ws_size,
                              hipStream_t stream)
{
    const float* x      = (const float*)d_in[0];
    const int*  cluster = (const int*)d_in[2];
    const int*  fgi     = (const int*)d_in[3];
    const float* ln1_g = (const float*)d_in[6];
    const float* ln1_b = (const float*)d_in[7];
    const float* w_qkv = (const float*)d_in[8];
    const float* b_qkv = (const float*)d_in[9];
    const float* w_o   = (const float*)d_in[10];
    const float* b_o   = (const float*)d_in[11];
    const float* ln2_g = (const float*)d_in[12];
    const float* ln2_b = (const float*)d_in[13];
    const float* w_fc  = (const float*)d_in[14];
    const float* b_fc  = (const float*)d_in[15];
    const float* w_proj= (const float*)d_in[16];
    const float* b_proj= (const float*)d_in[17];
    const float* w_down= (const float*)d_in[18];
    const float* b_down= (const float*)d_in[19];
    const float* w_up  = (const float*)d_in[20];
    const float* b_up  = (const float*)d_in[21];
    const float* bn3d_g= (const float*)d_in[22];
    const float* bn3d_b= (const float*)d_in[23];
    const float* n3_g  = (const float*)d_in[24];
    const float* n3_b  = (const float*)d_in[25];
    const float* vw_qkv= (const float*)d_in[26];
    const float* vb_qkv= (const float*)d_in[27];
    const float* vw_o  = (const float*)d_in[28];
    const float* vb_o  = (const float*)d_in[29];
    const float* bn1d_g= (const float*)d_in[30];
    const float* bn1d_b= (const float*)d_in[31];
    (void)in_sizes; (void)n_in; (void)out_size; (void)ws_size;

    float* out = (float*)d_out;

    // workspace layout (bytes), total ~185.1 MB
    char* w = (char*)d_ws;
    bf16*  QKV  = (bf16*)w;  w += (long long)NROWS * 3 * CDIM * 2;
    bf16*  H    = (bf16*)w;  w += (long long)NROWS * CDIM * 2;
    float* X2   = (float*)w; w += (long long)NROWS * CDIM * 4;
    bf16*  AO   = (bf16*)w;  w += (long long)NROWS * CDIM * 2;
    float* FFN  = (float*)w; w += (long long)NROWS * CDIM * 4;
    float* T1   = (float*)w; w += (long long)BATCH * SEQ * SEQ * 4;
    float* ADP  = (float*)w; w += (long long)NROWS * 16 * 4;
    float* FEAT = (float*)w; w += (long long)NFEAT * CDIM * 4;
    float* Y512 = (float*)w; w += (long long)NCLUST * CDIM * 4;
    bf16*  BN3D = (bf16*)w;  w += (long long)NCLUST * CDIM * 2;
    float* YG   = (float*)w; w += (long long)NGRID * CDIM * 4;
    bf16*  BN1D = (bf16*)w;  w += (long long)NVIEW * NGRID * CDIM * 2;

    dim3 blk(256);

    // ---- stage A: transformer block ----
    ln_kernel<<<NROWS, blk, 0, stream>>>(x, ln1_g, ln1_b, 0LL, H);

    gemm2<0,0,1,0,0><<<dim3(18, 65, 1), blk, 0, stream>>>(
        H, w_qkv, b_qkv, nullptr, QKV,
        NROWS, 3*CDIM, CDIM, CDIM, 3*CDIM, 3*CDIM, 0, 1.f, 0, 0LL, 0LL, 0, 0, 0);

    // ---- main attention via per-head MFMA GEMMs ----
    for (int h = 0; h < NHEAD; ++h) {
        gemm2<1,0,0,1,0><<<dim3(9, 9, BATCH), blk, 0, stream>>>(
            QKV + h * DHEAD, QKV + CDIM + h * DHEAD, nullptr, nullptr, T1,
            SEQ, SEQ, DHEAD, 3*CDIM, 3*CDIM, SEQ, 0, 0.125f, 0, 0LL, 0LL,
            (long long)SEQ * 3*CDIM, (long long)SEQ * 3*CDIM, (long long)SEQ * SEQ);

        softmax_aw_kernel<<<NROWS, blk, 0, stream>>>(T1, out, h == 0 ? 1 : 0);

        gemm_k<0,1,0,0,0><<<dim3(1, 17, BATCH), blk, 0, stream>>>(
            T1, QKV + 2*CDIM + h * DHEAD, nullptr, nullptr, AO + h * DHEAD,
            SEQ, DHEAD, SEQ, SEQ, 3*CDIM, CDIM, 0, 1.f, 0, 0LL, 0LL,
            (long long)SEQ * SEQ, (long long)SEQ * 3*CDIM, (long long)SEQ * CDIM);
    }

    // x2 = AO @ w_o + b_o + x   -> f32
    gemm2<0,0,1,1,1><<<dim3(6, 65, 1), blk, 0, stream>>>(
        AO, w_o, b_o, x, X2,
        NROWS, CDIM, CDIM, CDIM, CDIM, CDIM, CDIM, 1.f, 0, 0LL, 0LL, 0, 0, 0);

    ln_kernel<<<NROWS, blk, 0, stream>>>(X2, ln2_g, ln2_b, 0LL, H);

    // FC + proj in 2 row-chunks of 4100; bf16 MID shares T1
    {
        bf16* MID = (bf16*)T1;
        for (int cidx = 0; cidx < 2; ++cidx) {
            long long r0 = 4100LL * cidx;
            int m = 4100;
            gemm2<0,0,1,0,0><<<dim3(24, 33, 1), blk, 0, stream>>>(
                H + r0 * CDIM, w_fc, b_fc, nullptr, MID,
                m, 4*CDIM, CDIM, CDIM, 4*CDIM, 4*CDIM, 0, 1.f, 1, 0LL, 0LL, 0, 0, 0);
            gemm2<0,0,1,1,0><<<dim3(6, 33, 1), blk, 0, stream>>>(
                MID, w_proj, b_proj, nullptr, FFN + r0 * CDIM,
                m, CDIM, 4*CDIM, 4*CDIM, CDIM, CDIM, 0, 1.f, 0, 0LL, 0LL, 0, 0, 0);
        }
    }

    adp_down_kernel<<<NROWS, blk, 0, stream>>>(FFN, w_down, b_down, ADP);
    final_up_kernel<<<NROWS, blk, 0, stream>>>(ADP, w_up, b_up, X2, FFN, out, FEAT);

    // ---- stage B: cluster pooling + BN-GELU ----
    seg_kernel<<<NCLUST, blk, 0, stream>>>(FEAT, cluster, Y512);
    bn_gelu_kernel<<<CDIM, dim3(128), 0, stream>>>(Y512, bn3d_g, bn3d_b, 0LL, BN3D, NCLUST);

    // ---- stage C: 6 views ----
    const float inv_sqrt_c = 0.03608439182435161f; // 1/sqrt(768)
    for (int i = 0; i < NVIEW; ++i) {
        ln_kernel<<<NFEAT, blk, 0, stream>>>(FEAT, n3_g, n3_b, (long long)i * CDIM, H);

        gemm2<0,0,1,0,0><<<dim3(18, 64, 1), blk, 0, stream>>>(
            H, vw_qkv, vb_qkv, nullptr, QKV,
            NFEAT, 3*CDIM, CDIM, CDIM, 3*CDIM, 3*CDIM, 0, 1.f, 0,
            (long long)i * CDIM * 3*CDIM, (long long)i * 3*CDIM, 0, 0, 0);

        gemm2<1,0,0,1,0><<<dim3(8, 8, BATCH), blk, 0, stream>>>(
            QKV, QKV + CDIM, nullptr, nullptr, T1,
            GTOK, GTOK, CDIM, 3*CDIM, 3*CDIM, GTOK, 0, inv_sqrt_c, 0, 0LL, 0LL,
            (long long)GTOK * 3*CDIM, (long long)GTOK * 3*CDIM, (long long)GTOK * GTOK);

        softmax_rows<<<BATCH * GTOK, blk, 0, stream>>>(T1);

        gemm2<0,1,0,0,0><<<dim3(6, 8, BATCH), blk, 0, stream>>>(
            T1, QKV + 2*CDIM, nullptr, nullptr, AO,
            GTOK, CDIM, GTOK, GTOK, 3*CDIM, CDIM, 0, 1.f, 0, 0LL, 0LL,
            (long long)GTOK * GTOK, (long long)GTOK * 3*CDIM, (long long)GTOK * CDIM);

        gemm2<0,0,1,1,1><<<dim3(6, 64, 1), blk, 0, stream>>>(
            AO, vw_o, vb_o, FEAT, X2,
            NFEAT, CDIM, CDIM, CDIM, CDIM, CDIM, CDIM, 1.f, 0,
            (long long)i * CDIM * CDIM, (long long)i * CDIM, 0, 0, 0);

        seg_kernel<<<NGRID, blk, 0, stream>>>(X2, fgi + i * NFEAT, YG);
        bn_gelu_kernel<<<CDIM, dim3(128), 0, stream>>>(
            YG, bn1d_g, bn1d_b, (long long)i * CDIM,
            BN1D + (long long)i * NGRID * CDIM, NGRID);
    }

    // ---- final fusion ----
    fuse_final_kernel<<<NFEAT, blk, 0, stream>>>(FEAT, BN3D, BN1D, cluster, fgi, out);
}

// Round 13
// 3997.703 us; speedup vs baseline: 5.6095x; 1.4098x over previous
//
#include <hip/hip_runtime.h>
#include <math.h>
#include <float.h>

#define BATCH   8
#define SEQ     1025
#define GTOK    1024
#define CDIM    768
#define NHEAD   12
#define DHEAD   64
#define NVIEW   6
#define NCLUST  512
#define NGRID   1568
#define NROWS   8200
#define NFEAT   8192
#define SEGCAP  2048

typedef unsigned short bf16;
typedef __attribute__((ext_vector_type(8))) short bf16x8;
typedef __attribute__((ext_vector_type(4))) float f32x4;

__device__ __forceinline__ float b2f(bf16 u) {
    union { unsigned int i; float f; } v; v.i = ((unsigned int)u) << 16; return v.f;
}
__device__ __forceinline__ bf16 f2b(float f) {
    union { float f; unsigned int i; } v; v.f = f;
    unsigned int x = v.i;
    return (bf16)((x + 0x7fffu + ((x >> 16) & 1u)) >> 16);
}

__device__ __forceinline__ float block_reduce_sum(float v, float* red) {
    int tid = threadIdx.x;
    red[tid] = v; __syncthreads();
    for (int s = blockDim.x >> 1; s > 0; s >>= 1) {
        if (tid < s) red[tid] += red[tid + s];
        __syncthreads();
    }
    float r = red[0]; __syncthreads();
    return r;
}

__device__ __forceinline__ float gelu_exact(float v) {
    return 0.5f * v * (1.f + erff(v * 0.70710678118654752f));
}
__device__ __forceinline__ float quick_gelu(float v) {
    return v / (1.f + expf(-1.702f * v));
}

// ---------------------------------------------------------------------------
// LayerNorm: one block per row (f32 input, f32 gamma/beta, bf16 out)
// ---------------------------------------------------------------------------
__global__ __launch_bounds__(256)
void ln_kernel(const float* __restrict__ x, const float* __restrict__ g,
               const float* __restrict__ b, long long goff, bf16* __restrict__ out)
{
    __shared__ float red[256];
    long long row = blockIdx.x;
    int tid = threadIdx.x;
    long long base = row * CDIM;
    float v0 = x[base + tid], v1 = x[base + tid + 256], v2 = x[base + tid + 512];
    float mean = block_reduce_sum(v0 + v1 + v2, red) * (1.f / CDIM);
    float d0 = v0 - mean, d1 = v1 - mean, d2 = v2 - mean;
    float var = block_reduce_sum(d0 * d0 + d1 * d1 + d2 * d2, red) * (1.f / CDIM);
    float rstd = rsqrtf(var + 1e-5f);
    bf16* orow = out + base;
    orow[tid]       = f2b(d0 * rstd * g[goff + tid]       + b[goff + tid]);
    orow[tid + 256] = f2b(d1 * rstd * g[goff + tid + 256] + b[goff + tid + 256]);
    orow[tid + 512] = f2b(d2 * rstd * g[goff + tid + 512] + b[goff + tid + 512]);
}

// ---------------------------------------------------------------------------
// gemm_k: 64x64-tile MFMA GEMM (proven; kept for narrow-N / odd-K cases)
// ---------------------------------------------------------------------------
#define LDSK 40

template<int TRANSB, int ATY, int BSRC, int OTY, int RES>
__global__ __launch_bounds__(256)
void gemm_k(const void* __restrict__ Av, const void* __restrict__ B,
            const void* __restrict__ bias, const float* __restrict__ Res,
            void* __restrict__ Cv,
            int M, int N, int K, int lda, int ldb, int ldc, int ldres,
            float alpha, int act, long long boff, long long biasoff,
            long long sA, long long sB, long long sC)
{
    __shared__ short As[64][LDSK];
    __shared__ short Bs[64][LDSK];
    int bz = blockIdx.z;
    int tid = threadIdx.x;
    int m0 = blockIdx.y * 64, n0 = blockIdx.x * 64;
    long long Aoff = (long long)bz * sA;
    long long Boff = boff + (long long)bz * sB;

    int lane = tid & 63;
    int w = tid >> 6;
    int wr = w >> 1, wc = w & 1;
    int fr = lane & 15;
    int kg = lane >> 4;

    f32x4 acc[2][2] = {};

    for (int k0 = 0; k0 < K; k0 += 32) {
        {
            int r = tid >> 2, kb = (tid & 3) * 8;
            int gm = m0 + r;
            short tmp[8] = {};
            if (gm < M) {
                long long base = Aoff + (long long)gm * lda + k0 + kb;
                if (k0 + kb + 8 <= K) {
                    if (ATY == 0) {
                        *reinterpret_cast<uint4*>(tmp) =
                            *reinterpret_cast<const uint4*>((const bf16*)Av + base);
                    } else {
                        float4 f0 = *reinterpret_cast<const float4*>((const float*)Av + base);
                        float4 f1 = *reinterpret_cast<const float4*>((const float*)Av + base + 4);
                        tmp[0]=(short)f2b(f0.x); tmp[1]=(short)f2b(f0.y);
                        tmp[2]=(short)f2b(f0.z); tmp[3]=(short)f2b(f0.w);
                        tmp[4]=(short)f2b(f1.x); tmp[5]=(short)f2b(f1.y);
                        tmp[6]=(short)f2b(f1.z); tmp[7]=(short)f2b(f1.w);
                    }
                } else {
                    #pragma unroll
                    for (int j = 0; j < 8; ++j) {
                        if (k0 + kb + j < K)
                            tmp[j] = ATY ? (short)f2b(((const float*)Av)[base + j])
                                         : (short)((const bf16*)Av)[base + j];
                    }
                }
            }
            *reinterpret_cast<uint4*>(&As[r][kb]) = *reinterpret_cast<uint4*>(tmp);
        }
        {
            int col = tid >> 2, kb = (tid & 3) * 8;
            int gn = n0 + col;
            short tmp[8] = {};
            if (gn < N) {
                if (TRANSB) {
                    long long base = Boff + (long long)gn * ldb + k0 + kb;
                    if (k0 + kb + 8 <= K) {
                        if (BSRC == 0) {
                            *reinterpret_cast<uint4*>(tmp) =
                                *reinterpret_cast<const uint4*>((const bf16*)B + base);
                        } else {
                            float4 f0 = *reinterpret_cast<const float4*>((const float*)B + base);
                            float4 f1 = *reinterpret_cast<const float4*>((const float*)B + base + 4);
                            tmp[0]=(short)f2b(f0.x); tmp[1]=(short)f2b(f0.y);
                            tmp[2]=(short)f2b(f0.z); tmp[3]=(short)f2b(f0.w);
                            tmp[4]=(short)f2b(f1.x); tmp[5]=(short)f2b(f1.y);
                            tmp[6]=(short)f2b(f1.z); tmp[7]=(short)f2b(f1.w);
                        }
                    } else {
                        #pragma unroll
                        for (int j = 0; j < 8; ++j) {
                            if (k0 + kb + j < K)
                                tmp[j] = BSRC ? (short)f2b(((const float*)B)[base + j])
                                              : (short)((const bf16*)B)[base + j];
                        }
                    }
                } else {
                    #pragma unroll
                    for (int j = 0; j < 8; ++j) {
                        int kk = k0 + kb + j;
                        if (kk < K) {
                            long long bi = Boff + (long long)kk * ldb + gn;
                            tmp[j] = BSRC ? (short)f2b(((const float*)B)[bi])
                                          : (short)((const bf16*)B)[bi];
                        }
                    }
                }
            }
            *reinterpret_cast<uint4*>(&Bs[col][kb]) = *reinterpret_cast<uint4*>(tmp);
        }
        __syncthreads();

        bf16x8 a0 = *reinterpret_cast<const bf16x8*>(&As[wr * 32 + fr][kg * 8]);
        bf16x8 a1 = *reinterpret_cast<const bf16x8*>(&As[wr * 32 + 16 + fr][kg * 8]);
        bf16x8 b0 = *reinterpret_cast<const bf16x8*>(&Bs[wc * 32 + fr][kg * 8]);
        bf16x8 b1 = *reinterpret_cast<const bf16x8*>(&Bs[wc * 32 + 16 + fr][kg * 8]);
        acc[0][0] = __builtin_amdgcn_mfma_f32_16x16x32_bf16(a0, b0, acc[0][0], 0, 0, 0);
        acc[0][1] = __builtin_amdgcn_mfma_f32_16x16x32_bf16(a0, b1, acc[0][1], 0, 0, 0);
        acc[1][0] = __builtin_amdgcn_mfma_f32_16x16x32_bf16(a1, b0, acc[1][0], 0, 0, 0);
        acc[1][1] = __builtin_amdgcn_mfma_f32_16x16x32_bf16(a1, b1, acc[1][1], 0, 0, 0);
        __syncthreads();
    }

    #pragma unroll
    for (int m = 0; m < 2; ++m) {
        #pragma unroll
        for (int n = 0; n < 2; ++n) {
            #pragma unroll
            for (int i = 0; i < 4; ++i) {
                int gm = m0 + wr * 32 + m * 16 + kg * 4 + i;
                int gn = n0 + wc * 32 + n * 16 + fr;
                if (gm >= M || gn >= N) continue;
                float v = acc[m][n][i] * alpha;
                if (bias) v += BSRC ? ((const float*)bias)[biasoff + gn]
                                    : b2f(((const bf16*)bias)[biasoff + gn]);
                if (act == 1) v = quick_gelu(v);
                if (RES) v += Res[(long long)gm * ldres + gn];
                long long ci = sC * bz + (long long)gm * ldc + gn;
                if (OTY) ((float*)Cv)[ci] = v;
                else     ((bf16*)Cv)[ci] = f2b(v);
            }
        }
    }
}

// ---------------------------------------------------------------------------
// gemm2: 128x128-tile MFMA GEMM, BK=32, 8 waves (2x4), register-prefetch
// pipeline (stage k+1 global->regs during MFMA of k). Requires K % 32 == 0.
// Each wave: 64x32 quadrant, 4x2 frags, 8 MFMA + 6 ds_read_b128 per K-step.
// ---------------------------------------------------------------------------
template<int TRANSB, int ATY, int BSRC, int OTY, int RES>
__global__ __launch_bounds__(512)
void gemm2(const void* __restrict__ Av, const void* __restrict__ B,
           const void* __restrict__ bias, const float* __restrict__ Res,
           void* __restrict__ Cv,
           int M, int N, int K, int lda, int ldb, int ldc, int ldres,
           float alpha, int act, long long boff, long long biasoff,
           long long sA, long long sB, long long sC)
{
    __shared__ short As[128][LDSK];
    __shared__ short Bs[128][LDSK];
    int bz = blockIdx.z;
    int tid = threadIdx.x;               // 0..511
    int m0 = blockIdx.y * 128, n0 = blockIdx.x * 128;
    long long Aoff = (long long)bz * sA;
    long long Boff = boff + (long long)bz * sB;

    int lane = tid & 63;
    int w = tid >> 6;                    // 0..7
    int wr = w >> 2, wc = w & 3;         // 2 x 4 wave grid
    int fr = lane & 15;
    int kg = lane >> 4;

    int srow = tid >> 2;                 // stage row/col 0..127
    int skb  = (tid & 3) * 8;            // k sub-offset

    short ra[8], rb[8];

    auto loadA = [&](int kk) {
        int gm = m0 + srow;
        if (gm < M) {
            long long base = Aoff + (long long)gm * lda + kk + skb;
            if (ATY == 0) {
                *reinterpret_cast<uint4*>(ra) =
                    *reinterpret_cast<const uint4*>((const bf16*)Av + base);
            } else {
                float4 f0 = *reinterpret_cast<const float4*>((const float*)Av + base);
                float4 f1 = *reinterpret_cast<const float4*>((const float*)Av + base + 4);
                ra[0]=(short)f2b(f0.x); ra[1]=(short)f2b(f0.y);
                ra[2]=(short)f2b(f0.z); ra[3]=(short)f2b(f0.w);
                ra[4]=(short)f2b(f1.x); ra[5]=(short)f2b(f1.y);
                ra[6]=(short)f2b(f1.z); ra[7]=(short)f2b(f1.w);
            }
        } else {
            #pragma unroll
            for (int j = 0; j < 8; ++j) ra[j] = 0;
        }
    };
    auto loadB = [&](int kk) {
        int gn = n0 + srow;
        if (gn < N) {
            if (TRANSB) {
                long long base = Boff + (long long)gn * ldb + kk + skb;
                if (BSRC == 0) {
                    *reinterpret_cast<uint4*>(rb) =
                        *reinterpret_cast<const uint4*>((const bf16*)B + base);
                } else {
                    float4 f0 = *reinterpret_cast<const float4*>((const float*)B + base);
                    float4 f1 = *reinterpret_cast<const float4*>((const float*)B + base + 4);
                    rb[0]=(short)f2b(f0.x); rb[1]=(short)f2b(f0.y);
                    rb[2]=(short)f2b(f0.z); rb[3]=(short)f2b(f0.w);
                    rb[4]=(short)f2b(f1.x); rb[5]=(short)f2b(f1.y);
                    rb[6]=(short)f2b(f1.z); rb[7]=(short)f2b(f1.w);
                }
            } else {
                #pragma unroll
                for (int j = 0; j < 8; ++j) {
                    long long bi = Boff + (long long)(kk + skb + j) * ldb + gn;
                    rb[j] = BSRC ? (short)f2b(((const float*)B)[bi])
                                 : (short)((const bf16*)B)[bi];
                }
            }
        } else {
            #pragma unroll
            for (int j = 0; j < 8; ++j) rb[j] = 0;
        }
    };

    f32x4 acc[4][2] = {};

    loadA(0); loadB(0);
    for (int k0 = 0; k0 < K; k0 += 32) {
        *reinterpret_cast<uint4*>(&As[srow][skb]) = *reinterpret_cast<uint4*>(ra);
        *reinterpret_cast<uint4*>(&Bs[srow][skb]) = *reinterpret_cast<uint4*>(rb);
        __syncthreads();
        if (k0 + 32 < K) { loadA(k0 + 32); loadB(k0 + 32); }

        bf16x8 a[4], bq[2];
        #pragma unroll
        for (int m = 0; m < 4; ++m)
            a[m] = *reinterpret_cast<const bf16x8*>(&As[wr * 64 + m * 16 + fr][kg * 8]);
        #pragma unroll
        for (int n = 0; n < 2; ++n)
            bq[n] = *reinterpret_cast<const bf16x8*>(&Bs[wc * 32 + n * 16 + fr][kg * 8]);
        #pragma unroll
        for (int m = 0; m < 4; ++m)
            #pragma unroll
            for (int n = 0; n < 2; ++n)
                acc[m][n] = __builtin_amdgcn_mfma_f32_16x16x32_bf16(a[m], bq[n], acc[m][n], 0, 0, 0);
        __syncthreads();
    }

    #pragma unroll
    for (int m = 0; m < 4; ++m) {
        #pragma unroll
        for (int n = 0; n < 2; ++n) {
            #pragma unroll
            for (int i = 0; i < 4; ++i) {
                int gm = m0 + wr * 64 + m * 16 + kg * 4 + i;
                int gn = n0 + wc * 32 + n * 16 + fr;
                if (gm >= M || gn >= N) continue;
                float v = acc[m][n][i] * alpha;
                if (bias) v += BSRC ? ((const float*)bias)[biasoff + gn]
                                    : b2f(((const bf16*)bias)[biasoff + gn]);
                if (act == 1) v = quick_gelu(v);
                if (RES) v += Res[(long long)gm * ldres + gn];
                long long ci = sC * bz + (long long)gm * ldc + gn;
                if (OTY) ((float*)Cv)[ci] = v;
                else     ((bf16*)Cv)[ci] = f2b(v);
            }
        }
    }
}

// ---------------------------------------------------------------------------
// Fused softmax + attn_weight accumulate, LDS-staged row (1 read + 1 write)
// ---------------------------------------------------------------------------
__global__ __launch_bounds__(256)
void softmax_aw_kernel(float* __restrict__ T1, float* __restrict__ out, int first)
{
    __shared__ float red[256];
    __shared__ float srow[SEQ];
    long long r = blockIdx.x;
    float* sr = T1 + r * SEQ;
    float* aw = out + (long long)NROWS * CDIM + r * SEQ;
    int tid = threadIdx.x;

    float lmax = -FLT_MAX;
    for (int k = tid; k < SEQ; k += 256) {
        float v = sr[k];
        srow[k] = v;
        lmax = fmaxf(lmax, v);
    }
    red[tid] = lmax; __syncthreads();
    for (int st = 128; st > 0; st >>= 1) {
        if (tid < st) red[tid] = fmaxf(red[tid], red[tid + st]);
        __syncthreads();
    }
    float m = red[0]; __syncthreads();

    float ls = 0.f;
    for (int k = tid; k < SEQ; k += 256) {
        float p = expf(srow[k] - m);
        srow[k] = p; ls += p;
    }
    float Z = block_reduce_sum(ls, red);
    float inv = 1.f / fmaxf(Z, 1e-30f);
    const float hscale = 1.f / (float)NHEAD;
    for (int k = tid; k < SEQ; k += 256) {
        float p = srow[k] * inv;
        sr[k] = p;
        aw[k] = (first ? 0.f : aw[k]) + p * hscale;
    }
}

// ---------------------------------------------------------------------------
// Row softmax (view attention), LDS-staged row
// ---------------------------------------------------------------------------
__global__ __launch_bounds__(256)
void softmax_rows(float* __restrict__ s)
{
    __shared__ float red[256];
    __shared__ float srow[GTOK];
    long long row = blockIdx.x;
    float* sr = s + row * GTOK;
    int tid = threadIdx.x;
    float lmax = -FLT_MAX;
    #pragma unroll
    for (int i = 0; i < 4; ++i) {
        float v = sr[tid + i * 256];
        srow[tid + i * 256] = v;
        lmax = fmaxf(lmax, v);
    }
    red[tid] = lmax; __syncthreads();
    for (int st = 128; st > 0; st >>= 1) {
        if (tid < st) red[tid] = fmaxf(red[tid], red[tid + st]);
        __syncthreads();
    }
    float m = red[0]; __syncthreads();
    float ls = 0.f;
    #pragma unroll
    for (int i = 0; i < 4; ++i) {
        float p = expf(srow[tid + i * 256] - m);
        srow[tid + i * 256] = p; ls += p;
    }
    float Z = block_reduce_sum(ls, red);
    float inv = 1.f / fmaxf(Z, 1e-30f);
    #pragma unroll
    for (int i = 0; i < 4; ++i) sr[tid + i * 256] = srow[tid + i * 256] * inv;
}

// ---------------------------------------------------------------------------
// adapter down: adp1 = gelu(ffn @ w_down + b_down) -> f32 (NROWS,16)
// ---------------------------------------------------------------------------
__global__ __launch_bounds__(256)
void adp_down_kernel(const float* __restrict__ ffn, const float* __restrict__ w,
                     const float* __restrict__ bias, float* __restrict__ out)
{
    __shared__ float rowsh[CDIM];
    __shared__ float red[256];
    long long row = blockIdx.x;
    int tid = threadIdx.x;
    for (int c = tid; c < CDIM; c += 256) rowsh[c] = ffn[row * CDIM + c];
    __syncthreads();
    int n = tid >> 4;
    int part = tid & 15;
    float s = 0.f;
    for (int i = part; i < CDIM; i += 16) s += rowsh[i] * w[i * 16 + n];
    red[tid] = s; __syncthreads();
    if (part == 0) {
        float t = 0.f;
        #pragma unroll
        for (int p = 0; p < 16; ++p) t += red[n * 16 + p];
        t += bias[n];
        out[row * 16 + n] = gelu_exact(t);
    }
}

// ---------------------------------------------------------------------------
// final up + residuals: v = x2 + ffn + 0.5*(adp1 @ w_up + b_up)   (f32)
// ---------------------------------------------------------------------------
__global__ __launch_bounds__(256)
void final_up_kernel(const float* __restrict__ adp1, const float* __restrict__ w_up,
                     const float* __restrict__ b_up, const float* __restrict__ x2,
                     const float* __restrict__ ffn, float* __restrict__ out,
                     float* __restrict__ feat)
{
    __shared__ float a[16];
    long long row = blockIdx.x;
    int tid = threadIdx.x;
    if (tid < 16) a[tid] = adp1[row * 16 + tid];
    __syncthreads();
    int b = (int)(row / SEQ);
    int s = (int)(row % SEQ);
    #pragma unroll
    for (int i = 0; i < 3; ++i) {
        int c = tid + i * 256;
        float acc = b_up[c];
        #pragma unroll
        for (int k = 0; k < 16; ++k) acc += a[k] * w_up[k * CDIM + c];
        float v = x2[row * CDIM + c] + ffn[row * CDIM + c] + 0.5f * acc;
        out[row * CDIM + c] = v;
        if (s > 0)
            feat[((long long)b * GTOK + (s - 1)) * CDIM + c] = v;
    }
}

// ---------------------------------------------------------------------------
// Deterministic segment max+mean, compacted (round 11, proven)
// ---------------------------------------------------------------------------
__global__ __launch_bounds__(256)
void seg_kernel(const float* __restrict__ feat, const int* __restrict__ idx,
                float* __restrict__ y)
{
    __shared__ int sidx[NFEAT];
    __shared__ int list[SEGCAP];
    __shared__ int offs[256];
    int seg = blockIdx.x;
    int tid = threadIdx.x;
    for (int j = tid; j < NFEAT; j += 256) sidx[j] = idx[j];
    __syncthreads();

    int base = tid * 32;
    int cnt = 0;
    #pragma unroll
    for (int i = 0; i < 32; ++i) cnt += (sidx[base + i] == seg) ? 1 : 0;
    offs[tid] = cnt;
    __syncthreads();
    for (int st = 1; st < 256; st <<= 1) {
        int v = (tid >= st) ? offs[tid - st] : 0;
        __syncthreads();
        offs[tid] += v;
        __syncthreads();
    }
    int total = offs[255];
    int pos = offs[tid] - cnt;
    __syncthreads();

    float mx0 = -FLT_MAX, mx1 = -FLT_MAX, mx2 = -FLT_MAX;
    float s0 = 0.f, s1 = 0.f, s2 = 0.f;

    if (total <= SEGCAP) {
        #pragma unroll
        for (int i = 0; i < 32; ++i) {
            int j = base + i;
            if (sidx[j] == seg) list[pos++] = j;
        }
        __syncthreads();
        for (int i = 0; i < total; ++i) {
            const float* fr = feat + (long long)list[i] * CDIM;
            float v0 = fr[tid], v1 = fr[tid + 256], v2 = fr[tid + 512];
            s0 += v0; s1 += v1; s2 += v2;
            mx0 = fmaxf(mx0, v0); mx1 = fmaxf(mx1, v1); mx2 = fmaxf(mx2, v2);
        }
    } else {
        for (int j = 0; j < NFEAT; ++j) {
            if (sidx[j] == seg) {
                const float* fr = feat + (long long)j * CDIM;
                float v0 = fr[tid], v1 = fr[tid + 256], v2 = fr[tid + 512];
                s0 += v0; s1 += v1; s2 += v2;
                mx0 = fmaxf(mx0, v0); mx1 = fmaxf(mx1, v1); mx2 = fmaxf(mx2, v2);
            }
        }
    }

    if (total == 0) { mx0 = mx1 = mx2 = 0.f; }
    float inv = 1.f / (float)(total > 0 ? total : 1);
    float* yr = y + (long long)seg * CDIM;
    yr[tid]       = mx0 + s0 * inv;
    yr[tid + 256] = mx1 + s1 * inv;
    yr[tid + 512] = mx2 + s2 * inv;
}

// ---------------------------------------------------------------------------
// BatchNorm over rows (two-pass) + exact GELU -> bf16
// ---------------------------------------------------------------------------
__global__ __launch_bounds__(128)
void bn_gelu_kernel(const float* __restrict__ y, const float* __restrict__ g,
                    const float* __restrict__ b, long long goff,
                    bf16* __restrict__ out, int R)
{
    __shared__ float red[128];
    int c = blockIdx.x;
    int tid = threadIdx.x;
    float s = 0.f;
    for (int r = tid; r < R; r += 128) s += y[(long long)r * CDIM + c];
    float mean = block_reduce_sum(s, red) / (float)R;
    float ss = 0.f;
    for (int r = tid; r < R; r += 128) {
        float d = y[(long long)r * CDIM + c] - mean;
        ss += d * d;
    }
    float var = fmaxf(block_reduce_sum(ss, red) / (float)R, 0.f);
    float rstd = rsqrtf(var + 1e-5f);
    float gc = g[goff + c], bc = b[goff + c];
    for (int r = tid; r < R; r += 128) {
        float v = (y[(long long)r * CDIM + c] - mean) * rstd * gc + bc;
        out[(long long)r * CDIM + c] = f2b(gelu_exact(v));
    }
}

// ---------------------------------------------------------------------------
// Final fusion: cosine sims over 6 views, weighted sum, write f32 out rows
// ---------------------------------------------------------------------------
__global__ __launch_bounds__(256)
void fuse_final_kernel(const float* __restrict__ feat, const bf16* __restrict__ bn3d,
                       const bf16* __restrict__ bn1d, const int* __restrict__ cluster,
                       const int* __restrict__ fgi, float* __restrict__ out)
{
    __shared__ float red[256];
    __shared__ float simsh[NVIEW];
    int j = blockIdx.x;
    int tid = threadIdx.x;
    int b = j >> 10, g = j & 1023;
    const bf16* x3 = bn3d + (long long)cluster[j] * CDIM;
    float s = 0.f;
    for (int c = tid; c < CDIM; c += 256) { float v = b2f(x3[c]); s += v * v; }
    float nx3 = fmaxf(sqrtf(block_reduce_sum(s, red)), 1e-8f);

    for (int i = 0; i < NVIEW; ++i) {
        const bf16* p = bn1d + ((long long)i * NGRID + fgi[i * NFEAT + j]) * CDIM;
        float d = 0.f, nn = 0.f;
        for (int c = tid; c < CDIM; c += 256) {
            float pv = b2f(p[c]);
            d += pv * b2f(x3[c]); nn += pv * pv;
        }
        float D = block_reduce_sum(d, red);
        float Np = sqrtf(block_reduce_sum(nn, red));
        if (tid == 0) {
            float cosv = D / (fmaxf(Np, 1e-8f) * nx3);
            simsh[i] = (cosv + 1.f) * 0.5f;
        }
        __syncthreads();
    }
    float ssum = 0.f;
    #pragma unroll
    for (int i = 0; i < NVIEW; ++i) ssum += simsh[i];
    float invs = 1.f / fmaxf(ssum, 1e-20f);
    long long orow = ((long long)b * SEQ + 1 + g) * CDIM;
    for (int c = tid; c < CDIM; c += 256) {
        float acc = 0.f;
        #pragma unroll
        for (int i = 0; i < NVIEW; ++i) {
            const bf16* p = bn1d + ((long long)i * NGRID + fgi[i * NFEAT + j]) * CDIM;
            acc += simsh[i] * invs * b2f(p[c]);
        }
        out[orow + c] = feat[(long long)j * CDIM + c] + 0.3f * acc;
    }
}

// ---------------------------------------------------------------------------
// Host side
// ---------------------------------------------------------------------------
extern "C" void kernel_launch(void* const* d_in, const int* in_sizes, int n_in,
                              void* d_out, int out_size, void* d_ws, size_t ws_size,
                              hipStream_t stream)
{
    const float* x      = (const float*)d_in[0];
    const int*  cluster = (const int*)d_in[2];
    const int*  fgi     = (const int*)d_in[3];
    const float* ln1_g = (const float*)d_in[6];
    const float* ln1_b = (const float*)d_in[7];
    const float* w_qkv = (const float*)d_in[8];
    const float* b_qkv = (const float*)d_in[9];
    const float* w_o   = (const float*)d_in[10];
    const float* b_o   = (const float*)d_in[11];
    const float* ln2_g = (const float*)d_in[12];
    const float* ln2_b = (const float*)d_in[13];
    const float* w_fc  = (const float*)d_in[14];
    const float* b_fc  = (const float*)d_in[15];
    const float* w_proj= (const float*)d_in[16];
    const float* b_proj= (const float*)d_in[17];
    const float* w_down= (const float*)d_in[18];
    const float* b_down= (const float*)d_in[19];
    const float* w_up  = (const float*)d_in[20];
    const float* b_up  = (const float*)d_in[21];
    const float* bn3d_g= (const float*)d_in[22];
    const float* bn3d_b= (const float*)d_in[23];
    const float* n3_g  = (const float*)d_in[24];
    const float* n3_b  = (const float*)d_in[25];
    const float* vw_qkv= (const float*)d_in[26];
    const float* vb_qkv= (const float*)d_in[27];
    const float* vw_o  = (const float*)d_in[28];
    const float* vb_o  = (const float*)d_in[29];
    const float* bn1d_g= (const float*)d_in[30];
    const float* bn1d_b= (const float*)d_in[31];
    (void)in_sizes; (void)n_in; (void)out_size; (void)ws_size;

    float* out = (float*)d_out;

    // workspace layout (bytes), total ~185.1 MB
    char* w = (char*)d_ws;
    bf16*  QKV  = (bf16*)w;  w += (long long)NROWS * 3 * CDIM * 2;
    bf16*  H    = (bf16*)w;  w += (long long)NROWS * CDIM * 2;
    float* X2   = (float*)w; w += (long long)NROWS * CDIM * 4;
    bf16*  AO   = (bf16*)w;  w += (long long)NROWS * CDIM * 2;
    float* FFN  = (float*)w; w += (long long)NROWS * CDIM * 4;
    float* T1   = (float*)w; w += (long long)BATCH * SEQ * SEQ * 4;
    float* ADP  = (float*)w; w += (long long)NROWS * 16 * 4;
    float* FEAT = (float*)w; w += (long long)NFEAT * CDIM * 4;
    float* Y512 = (float*)w; w += (long long)NCLUST * CDIM * 4;
    bf16*  BN3D = (bf16*)w;  w += (long long)NCLUST * CDIM * 2;
    float* YG   = (float*)w; w += (long long)NGRID * CDIM * 4;
    bf16*  BN1D = (bf16*)w;  w += (long long)NVIEW * NGRID * CDIM * 2;

    dim3 blk(256), blk512(512);

    // ---- stage A: transformer block ----
    ln_kernel<<<NROWS, blk, 0, stream>>>(x, ln1_g, ln1_b, 0LL, H);

    gemm2<0,0,1,0,0><<<dim3(18, 65, 1), blk512, 0, stream>>>(
        H, w_qkv, b_qkv, nullptr, QKV,
        NROWS, 3*CDIM, CDIM, CDIM, 3*CDIM, 3*CDIM, 0, 1.f, 0, 0LL, 0LL, 0, 0, 0);

    // ---- main attention via per-head MFMA GEMMs ----
    for (int h = 0; h < NHEAD; ++h) {
        gemm2<1,0,0,1,0><<<dim3(9, 9, BATCH), blk512, 0, stream>>>(
            QKV + h * DHEAD, QKV + CDIM + h * DHEAD, nullptr, nullptr, T1,
            SEQ, SEQ, DHEAD, 3*CDIM, 3*CDIM, SEQ, 0, 0.125f, 0, 0LL, 0LL,
            (long long)SEQ * 3*CDIM, (long long)SEQ * 3*CDIM, (long long)SEQ * SEQ);

        softmax_aw_kernel<<<NROWS, blk, 0, stream>>>(T1, out, h == 0 ? 1 : 0);

        gemm_k<0,1,0,0,0><<<dim3(1, 17, BATCH), blk, 0, stream>>>(
            T1, QKV + 2*CDIM + h * DHEAD, nullptr, nullptr, AO + h * DHEAD,
            SEQ, DHEAD, SEQ, SEQ, 3*CDIM, CDIM, 0, 1.f, 0, 0LL, 0LL,
            (long long)SEQ * SEQ, (long long)SEQ * 3*CDIM, (long long)SEQ * CDIM);
    }

    // x2 = AO @ w_o + b_o + x   -> f32
    gemm2<0,0,1,1,1><<<dim3(6, 65, 1), blk512, 0, stream>>>(
        AO, w_o, b_o, x, X2,
        NROWS, CDIM, CDIM, CDIM, CDIM, CDIM, CDIM, 1.f, 0, 0LL, 0LL, 0, 0, 0);

    ln_kernel<<<NROWS, blk, 0, stream>>>(X2, ln2_g, ln2_b, 0LL, H);

    // FC + proj in 2 row-chunks of 4100; bf16 MID shares T1
    {
        bf16* MID = (bf16*)T1;
        for (int cidx = 0; cidx < 2; ++cidx) {
            long long r0 = 4100LL * cidx;
            int m = 4100;
            gemm2<0,0,1,0,0><<<dim3(24, 33, 1), blk512, 0, stream>>>(
                H + r0 * CDIM, w_fc, b_fc, nullptr, MID,
                m, 4*CDIM, CDIM, CDIM, 4*CDIM, 4*CDIM, 0, 1.f, 1, 0LL, 0LL, 0, 0, 0);
            gemm2<0,0,1,1,0><<<dim3(6, 33, 1), blk512, 0, stream>>>(
                MID, w_proj, b_proj, nullptr, FFN + r0 * CDIM,
                m, CDIM, 4*CDIM, 4*CDIM, CDIM, CDIM, 0, 1.f, 0, 0LL, 0LL, 0, 0, 0);
        }
    }

    adp_down_kernel<<<NROWS, blk, 0, stream>>>(FFN, w_down, b_down, ADP);
    final_up_kernel<<<NROWS, blk, 0, stream>>>(ADP, w_up, b_up, X2, FFN, out, FEAT);

    // ---- stage B: cluster pooling + BN-GELU ----
    seg_kernel<<<NCLUST, blk, 0, stream>>>(FEAT, cluster, Y512);
    bn_gelu_kernel<<<CDIM, dim3(128), 0, stream>>>(Y512, bn3d_g, bn3d_b, 0LL, BN3D, NCLUST);

    // ---- stage C: 6 views ----
    const float inv_sqrt_c = 0.03608439182435161f; // 1/sqrt(768)
    for (int i = 0; i < NVIEW; ++i) {
        ln_kernel<<<NFEAT, blk, 0, stream>>>(FEAT, n3_g, n3_b, (long long)i * CDIM, H);

        gemm2<0,0,1,0,0><<<dim3(18, 64, 1), blk512, 0, stream>>>(
            H, vw_qkv, vb_qkv, nullptr, QKV,
            NFEAT, 3*CDIM, CDIM, CDIM, 3*CDIM, 3*CDIM, 0, 1.f, 0,
            (long long)i * CDIM * 3*CDIM, (long long)i * 3*CDIM, 0, 0, 0);

        gemm2<1,0,0,1,0><<<dim3(8, 8, BATCH), blk512, 0, stream>>>(
            QKV, QKV + CDIM, nullptr, nullptr, T1,
            GTOK, GTOK, CDIM, 3*CDIM, 3*CDIM, GTOK, 0, inv_sqrt_c, 0, 0LL, 0LL,
            (long long)GTOK * 3*CDIM, (long long)GTOK * 3*CDIM, (long long)GTOK * GTOK);

        softmax_rows<<<BATCH * GTOK, blk, 0, stream>>>(T1);

        gemm2<0,1,0,0,0><<<dim3(6, 8, BATCH), blk512, 0, stream>>>(
            T1, QKV + 2*CDIM, nullptr, nullptr, AO,
            GTOK, CDIM, GTOK, GTOK, 3*CDIM, CDIM, 0, 1.f, 0, 0LL, 0LL,
            (long long)GTOK * GTOK, (long long)GTOK * 3*CDIM, (long long)GTOK * CDIM);

        gemm2<0,0,1,1,1><<<dim3(6, 64, 1), blk512, 0, stream>>>(
            AO, vw_o, vb_o, FEAT, X2,
            NFEAT, CDIM, CDIM, CDIM, CDIM, CDIM, CDIM, 1.f, 0,
            (long long)i * CDIM * CDIM, (long long)i * CDIM, 0, 0, 0);

        seg_kernel<<<NGRID, blk, 0, stream>>>(X2, fgi + i * NFEAT, YG);
        bn_gelu_kernel<<<CDIM, dim3(128), 0, stream>>>(
            YG, bn1d_g, bn1d_b, (long long)i * CDIM,
            BN1D + (long long)i * NGRID * CDIM, NGRID);
    }

    // ---- final fusion ----
    fuse_final_kernel<<<NFEAT, blk, 0, stream>>>(FEAT, BN3D, BN1D, cluster, fgi, out);
}